// Round 6
// baseline (601.846 us; speedup 1.0000x reference)
//
#include <hip/hip_runtime.h>
#include <hip/hip_bf16.h>

#define B_SZ 4
#define L_SEQ 1024
#define D_MODEL 1024
#define DF_FF 4096
#define E_PER_B 32768
#define R_REL 64
#define M_ROWS (B_SZ * L_SEQ)   // 4096

typedef __attribute__((ext_vector_type(8))) short bf16x8;
typedef __attribute__((ext_vector_type(4))) float f32x4;

__device__ inline float b2f(unsigned short u) {
    union { unsigned int i; float f; } x; x.i = ((unsigned int)u) << 16; return x.f;
}
__device__ inline unsigned short f2b(float f) {
    union { float f; unsigned int u; } x; x.f = f;
    unsigned int r = x.u + 0x7FFFu + ((x.u >> 16) & 1u);
    return (unsigned short)(r >> 16);
}

#define GLOBAL_CAST(p) ((const __attribute__((address_space(1))) void*)(p))
#define LDS_CAST(p)    ((__attribute__((address_space(3))) void*)(p))

#define BT_QKV (1024u * 3072u)           // per-batch QKV stride
#define SEXT_M 1152                      // S_ext rows per batch: 1024 src + 128 relPad
#define LDA_WV 1088                      // Awv K width: 1024 (A) + 64 (G)
#define LDB_WVP 1152                     // Bwv' row stride (K padded to 18*64)
#define BT_WVP (1024u * 1152u)           // per-batch Bwv' stride

// ---------------- fused prep: weights + relPad + bias + LN0(bf16) + zero(A|G) ----------------
__global__ void prep_all(const float* __restrict__ Wq, const float* __restrict__ Wk,
                         const float* __restrict__ Wv, const float* __restrict__ Wo,
                         const float* __restrict__ W1, const float* __restrict__ W2,
                         const float* __restrict__ rel, const float* __restrict__ bq,
                         const float* __restrict__ hidden,
                         const float* __restrict__ ln0_g, const float* __restrict__ ln0_b,
                         unsigned short* __restrict__ Wqkv_t, unsigned short* __restrict__ Wo_t,
                         unsigned short* __restrict__ W1_t, unsigned short* __restrict__ W2_t,
                         unsigned short* __restrict__ relbPad,
                         float* __restrict__ bqkv,
                         unsigned short* __restrict__ Xn_b16,
                         float* __restrict__ zeroReg) {
    __shared__ float tile[32][33];
    __shared__ float sb1[4], sb2[4];
    const int id = blockIdx.x, tid = threadIdx.x;
    if (id < 12288) {
        const float* src; unsigned short* dst; int K, N, x, y;
        if (id < 4096) {
            const int seg = id >> 10, t = id & 1023;
            K = 1024; N = 1024; x = t & 31; y = t >> 5;
            src = (seg == 0) ? Wq : (seg == 1) ? Wk : (seg == 2) ? Wv : Wo;
            dst = (seg == 3) ? Wo_t : (Wqkv_t + (size_t)seg * 1048576);
        } else if (id < 8192) {
            const int t = id - 4096; K = 1024; N = 4096; x = t & 127; y = t >> 7;
            src = W1; dst = W1_t;
        } else {
            const int t = id - 8192; K = 4096; N = 1024; x = t & 31; y = t >> 5;
            src = W2; dst = W2_t;
        }
        const int n0 = x * 32, k0 = y * 32, tx = tid & 31, ty = tid >> 5;
#pragma unroll
        for (int r = 0; r < 32; r += 8)
            tile[ty + r][tx] = src[(size_t)(k0 + ty + r) * N + (n0 + tx)];
        __syncthreads();
#pragma unroll
        for (int r = 0; r < 32; r += 8)
            dst[(size_t)(n0 + ty + r) * K + (k0 + tx)] = f2b(tile[tx][ty + r]);
    } else if (id < 12800) {
        const int i = (id - 12288) * 256 + tid;            // 131072
        relbPad[i] = (i < 65536) ? f2b(rel[i]) : (unsigned short)0;
    } else if (id < 12812) {
        const int i = (id - 12800) * 256 + tid;            // 3072
        bqkv[i] = (i < 1024) ? bq[i] : 0.0f;
    } else if (id < 16908) {
        // LN0 row -> bf16
        const int row = id - 12812, t = tid;
        const size_t base = (size_t)row * 1024 + t * 4;
        float4 xv = *(const float4*)(hidden + base);
        float x0 = xv.x, x1 = xv.y, x2 = xv.z, x3 = xv.w;
        float s = x0 + x1 + x2 + x3;
#pragma unroll
        for (int o = 32; o > 0; o >>= 1) s += __shfl_down(s, o);
        if ((t & 63) == 0) sb1[t >> 6] = s;
        __syncthreads();
        const float mu = (sb1[0] + sb1[1] + sb1[2] + sb1[3]) * (1.0f / 1024.0f);
        const float d0 = x0 - mu, d1 = x1 - mu, d2 = x2 - mu, d3 = x3 - mu;
        float s2 = d0 * d0 + d1 * d1 + d2 * d2 + d3 * d3;
#pragma unroll
        for (int o = 32; o > 0; o >>= 1) s2 += __shfl_down(s2, o);
        if ((t & 63) == 0) sb2[t >> 6] = s2;
        __syncthreads();
        const float var = (sb2[0] + sb2[1] + sb2[2] + sb2[3]) * (1.0f / 1024.0f);
        const float rstd = rsqrtf(var + 1e-6f);
        const float4 gv = *(const float4*)(ln0_g + t * 4);
        const float4 bv = *(const float4*)(ln0_b + t * 4);
        ushort4 ob;
        ob.x = f2b(d0 * rstd * gv.x + bv.x);
        ob.y = f2b(d1 * rstd * gv.y + bv.y);
        ob.z = f2b(d2 * rstd * gv.z + bv.z);
        ob.w = f2b(d3 * rstd * gv.w + bv.w);
        *(ushort4*)(Xn_b16 + base) = ob;
    } else {
        const size_t base = (size_t)(id - 16908) * 4096 + tid * 4;
        const float4 z4 = make_float4(0.f, 0.f, 0.f, 0.f);
#pragma unroll
        for (int j = 0; j < 4; j++)
            *(float4*)(zeroReg + base + j * 1024) = z4;
    }
}

// 1D XCD swizzle: XCD = linear_id % 8; group all tile_n of a tile_m on one XCD.
__device__ inline void tile_swizzle(int id, int ntn, int& tm, int& tn) {
    tm = ((id & 7) + ((id >> 3) / ntn) * 8) * 128;
    tn = ((id >> 3) % ntn) * 128;
}
__device__ inline void tsw256(int id, int ntn, int& tm, int& tn) {
    tm = ((id & 7) + ((id >> 3) / ntn) * 8) * 256;
    tn = ((id >> 3) % ntn) * 256;
}

// ---------------- GEMM: 16x16x32 MFMA core (known-good: 0 LDS conflicts) ----------------
#define GEMM_BODY(GA, LDA_, GB, LDB_, KLEN)                                                 \
    f32x4 acc[4][4];                                                                        \
    _Pragma("unroll") for (int i = 0; i < 4; i++)                                           \
        _Pragma("unroll") for (int j = 0; j < 4; j++) acc[i][j] = (f32x4)0.0f;              \
    for (int k0 = 0; k0 < (KLEN); k0 += 64) {                                               \
        __syncthreads();                                                                    \
        _Pragma("unroll") for (int r = 0; r < 4; ++r) {                                     \
            __builtin_amdgcn_global_load_lds(GLOBAL_CAST((GA) + (size_t)r * 8 * (LDA_)),    \
                LDS_CAST(&lA[(wave * 32 + r * 8) * 64]), 16, 0, 0);                         \
            __builtin_amdgcn_global_load_lds(GLOBAL_CAST((GB) + (size_t)r * 8 * (LDB_)),    \
                LDS_CAST(&lB[(wave * 32 + r * 8) * 64]), 16, 0, 0);                         \
        }                                                                                   \
        (GA) += 64; (GB) += 64;                                                             \
        __builtin_amdgcn_s_waitcnt(0);                                                      \
        __syncthreads();                                                                    \
        _Pragma("unroll") for (int kk = 0; kk < 2; ++kk) {                                  \
            const int cb = kk * 4 + quad;                                                   \
            bf16x8 af[4], bf[4];                                                            \
            _Pragma("unroll") for (int i = 0; i < 4; i++) {                                 \
                const int ra = wm + i * 16 + l16;                                           \
                af[i] = *(const bf16x8*)&lA[ra * 64 + ((cb ^ (ra & 7)) * 8)];               \
                const int rb = wn + i * 16 + l16;                                           \
                bf[i] = *(const bf16x8*)&lB[rb * 64 + ((cb ^ (rb & 7)) * 8)];               \
            }                                                                               \
            _Pragma("unroll") for (int mi = 0; mi < 4; mi++)                                \
                _Pragma("unroll") for (int ni = 0; ni < 4; ni++)                            \
                    acc[mi][ni] = __builtin_amdgcn_mfma_f32_16x16x32_bf16(                  \
                        af[mi], bf[ni], acc[mi][ni], 0, 0, 0);                              \
        }                                                                                   \
    }

// ================= 256x256 pipelined GEMM (reg-dbuf fragments, reads 1 phase early) =========
// 512 thr = 8 waves (2M x 4N); per-wave C = 128x64; BK=64; LDS = 128KB (2buf x (A+B) x 32KB).
// K-step split into 4 C-quadrant phases (snake (0,0)->(0,1)->(1,1)->(1,0)); phase p issues the
// ds_reads for phase p+1's quadrant; MFMA consumes regs read at p-1, so the counted
// lgkmcnt(R_this) retires p-1's reads at ~zero cost. 24 b128/K-tile/wave (minimum).
// Stage units == read sets: A-unit QM = rows {QM*64..+63, 128+QM*64..+63};
// B-unit QN = stripes {64b + QN*32 .. +31}. 2 global_load_lds per phase uniformly.
// Counted vmcnt(4) at P3/P7 only (>=2-phase flight); one s_barrier per phase.
// WAR safety: every stage targets a region whose last read-ISSUE was >=2 phases back
// (those reads retired by each wave's lgkm wait before the intervening barrier).
#define ST_Aq(bufc, QM, kt) { \
    _Pragma("unroll") for (int j_ = 0; j_ < 2; j_++) { \
        const int u_ = j_ * 8 + wv; \
        const int lr_ = ((u_ >> 3) * 128) + (QM) * 64 + ((u_ & 7) * 8); \
        __builtin_amdgcn_global_load_lds(GLOBAL_CAST(Ag + (size_t)lr_ * lda + (kt) * 64), \
            LDS_CAST(&ls[bufc][0][lr_ * 64]), 16, 0, 0); } }
#define ST_Bq(bufc, QN, kt) { \
    _Pragma("unroll") for (int j_ = 0; j_ < 2; j_++) { \
        const int u_ = j_ * 8 + wv; \
        const int lr_ = ((u_ >> 2) * 64) + (QN) * 32 + ((u_ & 3) * 8); \
        __builtin_amdgcn_global_load_lds(GLOBAL_CAST(Bg + (size_t)lr_ * ldb + (kt) * 64), \
            LDS_CAST(&ls[bufc][1][lr_ * 64]), 16, 0, 0); } }

#define RD_A(SLOT, bufc, QM) { \
    _Pragma("unroll") for (int m4_ = 0; m4_ < 4; m4_++) \
        _Pragma("unroll") for (int kk_ = 0; kk_ < 2; kk_++) \
            SLOT[m4_][kk_] = *(const bf16x8*)&ls[bufc][0][ \
                (wm * 128 + (QM) * 64 + m4_ * 16 + l16) * 64 + (((kk_ * 4 + quad) ^ (l16 & 7)) * 8)]; }
#define RD_B(SLOT, bufc, QN) { \
    _Pragma("unroll") for (int n2_ = 0; n2_ < 2; n2_++) \
        _Pragma("unroll") for (int kk_ = 0; kk_ < 2; kk_++) \
            SLOT[n2_][kk_] = *(const bf16x8*)&ls[bufc][1][ \
                (wc * 64 + (QN) * 32 + n2_ * 16 + l16) * 64 + (((kk_ * 4 + quad) ^ (l16 & 7)) * 8)]; }

#define VM4 asm volatile("s_waitcnt vmcnt(4)" ::: "memory");
#define VM0 asm volatile("s_waitcnt vmcnt(0)" ::: "memory");

#define PHX(STAGES, READS, LG, ASLOT, BSLOT, QM, QN, VMW) { \
    STAGES; READS; \
    asm volatile("s_waitcnt lgkmcnt(" #LG ")" ::: "memory"); \
    __builtin_amdgcn_sched_barrier(0); \
    __builtin_amdgcn_s_setprio(1); \
    _Pragma("unroll") for (int m4_ = 0; m4_ < 4; m4_++) \
        _Pragma("unroll") for (int n2_ = 0; n2_ < 2; n2_++) \
            _Pragma("unroll") for (int kk_ = 0; kk_ < 2; kk_++) \
                acc[(QM) * 4 + m4_][(QN) * 2 + n2_] = __builtin_amdgcn_mfma_f32_16x16x32_bf16( \
                    ASLOT[m4_][kk_], BSLOT[n2_][kk_], acc[(QM) * 4 + m4_][(QN) * 2 + n2_], 0, 0, 0); \
    __builtin_amdgcn_s_setprio(0); \
    VMW; \
    __builtin_amdgcn_s_barrier(); }

template<bool RELU, bool SPLITK>
__global__ __launch_bounds__(512, 2)
void gemm256(const unsigned short* __restrict__ A, int lda,
             const unsigned short* __restrict__ Bt, int ldb,
             const float* __restrict__ bias,
             unsigned short* __restrict__ C, size_t pstride,
             int N, int Kc, int ntn) {
    __shared__ unsigned short ls[2][2][16384];   // [buf][A/B][256 rows * 64]
    int tile_m, tile_n;
    tsw256(blockIdx.x, ntn, tile_m, tile_n);
    const int t = threadIdx.x;
    const int wv = t >> 6, lane = t & 63;
    const int wm = wv >> 2;                 // wave m-group 0..1 (128 rows)
    const int wc = wv & 3;                  // wave n-group 0..3 (64 cols)
    const int quad = lane >> 4, l16 = lane & 15;
    const int srow8 = lane >> 3;
    const int schunk = ((lane & 7) ^ srow8) * 8;
    const int z = SPLITK ? blockIdx.z : 0;
    const int kofs = z * Kc;

    const unsigned short* Ag = A + (size_t)(tile_m + srow8) * lda + kofs + schunk;
    const unsigned short* Bg = Bt + (size_t)(tile_n + srow8) * ldb + kofs + schunk;

    f32x4 acc[8][4];
#pragma unroll
    for (int i = 0; i < 8; i++)
#pragma unroll
        for (int j = 0; j < 4; j++) acc[i][j] = (f32x4)0.0f;
    bf16x8 a0f[4][2], a1f[4][2], b0f[2][2], b1f[2][2];

    // prologue: tile0 full -> buf0 (8 loads); tile1 A0,B1,A1 -> buf1 (6 loads; B0 at P1)
    ST_Aq(0, 0, 0) ST_Aq(0, 1, 0) ST_Bq(0, 0, 0) ST_Bq(0, 1, 0)
    ST_Aq(1, 0, 1) ST_Bq(1, 1, 1) ST_Aq(1, 1, 1)
    asm volatile("s_waitcnt vmcnt(6)" ::: "memory");
    __builtin_amdgcn_s_barrier();
    RD_A(a0f, 0, 0) RD_B(b0f, 0, 0)      // reads for P1's MFMA (retired by P1's lgkm wait)

    const int NI = Kc >> 7;              // 2 K-tiles per iteration (Kc % 128 == 0)
    for (int it = 0; it < NI - 1; ++it) {
        const int t1 = 2 * it + 1, s0 = 2 * it + 2, s1 = 2 * it + 3;
        PHX(ST_Bq(1, 0, t1), RD_B(b1f, 0, 1),                   4,  a0f, b0f, 0, 0, )
        PHX(ST_Aq(0, 0, s0), RD_A(a1f, 0, 1),                   8,  a0f, b1f, 0, 1, )
        PHX(ST_Bq(0, 1, s0), ,                                  0,  a1f, b1f, 1, 1, VM4)
        PHX(ST_Aq(0, 1, s0), RD_A(a0f, 1, 0) RD_B(b1f, 1, 0),   12, a1f, b0f, 1, 0, )
        PHX(ST_Bq(0, 0, s0), RD_B(b0f, 1, 1),                   4,  a0f, b1f, 0, 0, )
        PHX(ST_Aq(1, 0, s1), RD_A(a1f, 1, 1),                   8,  a0f, b0f, 0, 1, )
        PHX(ST_Bq(1, 1, s1), ,                                  0,  a1f, b0f, 1, 1, VM4)
        PHX(ST_Aq(1, 1, s1), RD_A(a0f, 0, 0) RD_B(b0f, 0, 0),   12, a1f, b1f, 1, 0, )
    }
    {   // final iteration: only tile (2*NI-1).B0 left to stage; drain at P3
        const int t1 = 2 * NI - 1;
        PHX(ST_Bq(1, 0, t1), RD_B(b1f, 0, 1),                   4,  a0f, b0f, 0, 0, )
        PHX(,                RD_A(a1f, 0, 1),                   8,  a0f, b1f, 0, 1, )
        PHX(,                ,                                  0,  a1f, b1f, 1, 1, VM0)
        PHX(,                RD_A(a0f, 1, 0) RD_B(b1f, 1, 0),   12, a1f, b0f, 1, 0, )
        PHX(,                RD_B(b0f, 1, 1),                   4,  a0f, b1f, 0, 0, )
        PHX(,                RD_A(a1f, 1, 1),                   8,  a0f, b0f, 0, 1, )
        PHX(,                ,                                  0,  a1f, b0f, 1, 1, )
        PHX(,                ,                                  0,  a1f, b1f, 1, 0, )
    }

    unsigned short* Co = C + (SPLITK ? (size_t)z * pstride : 0);
#pragma unroll
    for (int mi = 0; mi < 8; mi++) {
#pragma unroll
        for (int ni = 0; ni < 4; ni++) {
            const int col = tile_n + wc * 64 + ni * 16 + l16;
            const float bv = (SPLITK && z != 0) ? 0.0f : bias[col];
#pragma unroll
            for (int r = 0; r < 4; r++) {
                const int row = tile_m + wm * 128 + mi * 16 + quad * 4 + r;
                float v = acc[mi][ni][r] + bv;
                if (RELU) v = fmaxf(v, 0.0f);
                Co[(size_t)row * N + col] = f2b(v);
            }
        }
    }
}

// ---------------- S_ext GEMM + W' GEMM, merged (both depend on QKV + weights only) ----------------
__global__ __launch_bounds__(256, 4)
void sext_w(const unsigned short* __restrict__ QKV,
            const unsigned short* __restrict__ relPad,
            const unsigned short* __restrict__ Wo_t,
            unsigned short* __restrict__ Pbase,
            unsigned short* __restrict__ Bwvp, int Kc) {
    __shared__ unsigned short lA[128 * 64];
    __shared__ unsigned short lB[128 * 64];
    const int id = blockIdx.x, t = threadIdx.x;
    const int wave = t >> 6, lane = t & 63;
    const int wm = (wave >> 1) * 64, wn = (wave & 1) * 64;
    const int quad = lane >> 4, l16 = lane & 15;
    const int srow = lane >> 3;
    const int schunk = ((lane & 7) ^ srow) * 8;

    if (id >= 576) {   // ---- W' segment ----
        const int t2 = id - 576;
        const int b = t2 / 72, rem = t2 % 72;
        const int tile_m = (rem / 9) * 128;          // e
        const int tile_n = (rem % 9) * 128;          // s | 1024+r
        const unsigned short* gA = Wo_t + (size_t)(tile_m + wave * 32 + srow) * 1024 + schunk;
        const int brow = tile_n + wave * 32 + srow;
        const unsigned short* gB;
        size_t ldb;
        if (tile_n < 1024) {                          // V rows, natural layout
            gB = QKV + (size_t)b * BT_QKV + (size_t)brow * 3072 + 2048 + schunk;
            ldb = 3072;
        } else {                                      // relPad rows
            gB = relPad + (size_t)(brow - 1024) * 1024 + schunk;
            ldb = 1024;
        }
        GEMM_BODY(gA, 1024, gB, ldb, 1024)
        unsigned short* P = Bwvp + (size_t)b * BT_WVP;
#pragma unroll
        for (int mi = 0; mi < 4; mi++) {
#pragma unroll
            for (int ni = 0; ni < 4; ni++) {
                const int col = tile_n + wn + ni * 16 + l16;
#pragma unroll
                for (int r = 0; r < 4; r++) {
                    const int row = tile_m + wm + mi * 16 + quad * 4 + r;
                    P[(size_t)row * LDB_WVP + col] = f2b(acc[mi][ni][r]);
                }
            }
        }
        return;
    }

    // ---- sext segment ----
    const int bx = id % 72, b = (id / 72) & 3, z = id / 288;
    const int tile_m = (bx >> 3) * 128;
    const int tile_n = (bx & 7) * 128;
    const int kofs = z * Kc;
    const int arow = tile_m + wave * 32 + srow;
    const unsigned short* gA;
    size_t lda;
    if (tile_m < 1024) {   // K rows
        gA = QKV + (size_t)b * BT_QKV + (size_t)arow * 3072 + 1024 + kofs + schunk;
        lda = 3072;
    } else {               // relPad rows
        gA = relPad + (size_t)(arow - 1024) * 1024 + kofs + schunk;
        lda = 1024;
    }
    const unsigned short* gB = QKV + (size_t)b * BT_QKV
                                   + (size_t)(tile_n + wave * 32 + srow) * 3072 + kofs + schunk;
    GEMM_BODY(gA, lda, gB, 3072, Kc)
    unsigned short* P = Pbase + ((size_t)z * B_SZ + b) * (SEXT_M * 1024);
#pragma unroll
    for (int mi = 0; mi < 4; mi++) {
#pragma unroll
        for (int ni = 0; ni < 4; ni++) {
            const int col = tile_n + wn + ni * 16 + l16;
#pragma unroll
            for (int r = 0; r < 4; r++) {
                const int row = tile_m + wm + mi * 16 + quad * 4 + r;
                P[(size_t)row * 1024 + col] = f2b(acc[mi][ni][r]);
            }
        }
    }
}

// ---------------- wv' GEMM: attention-out = Awv @ Bwv'^T + bo, asymmetric split-K=2 ----------------
__global__ __launch_bounds__(256, 4)
void gemm_wv_splitk(const unsigned short* __restrict__ A,
                    const unsigned short* __restrict__ Bt,
                    const float* __restrict__ bias,
                    unsigned short* __restrict__ Pbase, size_t pstride) {
    __shared__ unsigned short lA[128 * 64];
    __shared__ unsigned short lB[128 * 64];
    int tile_m, tile_n;
    tile_swizzle(blockIdx.x, 8, tile_m, tile_n);
    const int z = blockIdx.z;
    const int kofs = z * 576;
    const int Kc = z ? 512 : 576;
    const int t = threadIdx.x;
    const int wave = t >> 6, lane = t & 63;
    const int wm = (wave >> 1) * 64, wn = (wave & 1) * 64;
    const int quad = lane >> 4, l16 = lane & 15;
    const int srow = lane >> 3;
    const int schunk = ((lane & 7) ^ srow) * 8;
    const unsigned short* gA = A + (size_t)(tile_m + wave * 32 + srow) * LDA_WV + kofs + schunk;
    const unsigned short* gB = Bt + (size_t)(tile_m >> 10) * BT_WVP
                                  + (size_t)(tile_n + wave * 32 + srow) * LDB_WVP + kofs + schunk;
    GEMM_BODY(gA, LDA_WV, gB, LDB_WVP, Kc)
    unsigned short* P = Pbase + (size_t)z * pstride;
#pragma unroll
    for (int mi = 0; mi < 4; mi++) {
#pragma unroll
        for (int ni = 0; ni < 4; ni++) {
            const int col = tile_n + wn + ni * 16 + l16;
            const float bv = (z == 0) ? bias[col] : 0.0f;
#pragma unroll
            for (int r = 0; r < 4; r++) {
                const int row = tile_m + wm + mi * 16 + quad * 4 + r;
                P[(size_t)row * 1024 + col] = f2b(acc[mi][ni][r] + bv);
            }
        }
    }
}

// ---------------- LayerNorm family (bf16 X + bf16 partials) ----------------
template<bool FINAL, int NR>
__global__ void ln_kernel(const unsigned short* __restrict__ Xb,
                          const unsigned short* __restrict__ Rbase, size_t rstride,
                          const float* __restrict__ g, const float* __restrict__ be,
                          unsigned short* __restrict__ ob16,
                          const float* __restrict__ hidden, float* __restrict__ fout) {
    __shared__ float sb1[4], sb2[4];
    const int row = blockIdx.x, t = threadIdx.x;
    const size_t base = (size_t)row * 1024 + t * 4;

    ushort4 xv = *(const ushort4*)(Xb + base);
    float x0 = b2f(xv.x), x1 = b2f(xv.y), x2 = b2f(xv.z), x3 = b2f(xv.w);
#pragma unroll
    for (int r = 0; r < NR; r++) {
        ushort4 rv = *(const ushort4*)(Rbase + r * rstride + base);
        x0 += b2f(rv.x); x1 += b2f(rv.y); x2 += b2f(rv.z); x3 += b2f(rv.w);
    }
    float s = x0 + x1 + x2 + x3;
#pragma unroll
    for (int o = 32; o > 0; o >>= 1) s += __shfl_down(s, o);
    if ((t & 63) == 0) sb1[t >> 6] = s;
    __syncthreads();
    const float mu = (sb1[0] + sb1[1] + sb1[2] + sb1[3]) * (1.0f / 1024.0f);

    const float d0 = x0 - mu, d1 = x1 - mu, d2 = x2 - mu, d3 = x3 - mu;
    float s2 = d0 * d0 + d1 * d1 + d2 * d2 + d3 * d3;
#pragma unroll
    for (int o = 32; o > 0; o >>= 1) s2 += __shfl_down(s2, o);
    if ((t & 63) == 0) sb2[t >> 6] = s2;
    __syncthreads();
    const float var = (sb2[0] + sb2[1] + sb2[2] + sb2[3]) * (1.0f / 1024.0f);
    const float rstd = rsqrtf(var + 1e-6f);

    const float4 gv = *(const float4*)(g + t * 4);
    const float4 bv = *(const float4*)(be + t * 4);
    const float y0 = d0 * rstd * gv.x + bv.x;
    const float y1 = d1 * rstd * gv.y + bv.y;
    const float y2 = d2 * rstd * gv.z + bv.z;
    const float y3 = d3 * rstd * gv.w + bv.w;

    if (!FINAL) {
        ushort4 ob; ob.x = f2b(y0); ob.y = f2b(y1); ob.z = f2b(y2); ob.w = f2b(y3);
        *(ushort4*)(ob16 + base) = ob;
    } else {
        const float4 hv = *(const float4*)(hidden + base);
        const float e0 = y0 > 0.0f ? y0 : expm1f(y0);
        const float e1 = y1 > 0.0f ? y1 : expm1f(y1);
        const float e2 = y2 > 0.0f ? y2 : expm1f(y2);
        const float e3 = y3 > 0.0f ? y3 : expm1f(y3);
        float4 o; o.x = hv.x + e0; o.y = hv.y + e1; o.z = hv.z + e2; o.w = hv.w + e3;
        *(float4*)(fout + base) = o;
    }
}

// ---------------- dense edge phase ----------------
__global__ void edge_scatter(const unsigned short* __restrict__ S,
                             const int* __restrict__ src, const int* __restrict__ dst,
                             const int* __restrict__ rel,
                             float* __restrict__ A, float* __restrict__ G) {
    const size_t ZSTR = (size_t)B_SZ * SEXT_M * 1024;
    const int gg = blockIdx.x * 256 + threadIdx.x;   // B*E = 131072
    const int b = gg >> 15;
    const int s = src[gg], d = dst[gg], r = rel[gg];
    const size_t sbase = ((size_t)b * SEXT_M + s) * 1024 + d;
    const size_t tbase = ((size_t)b * SEXT_M + 1024 + r) * 1024 + d;
    const float sval = b2f(S[sbase]) + b2f(S[sbase + ZSTR]);
    const float tval = b2f(S[tbase]) + b2f(S[tbase + ZSTR]);
    float sc = (sval + tval) * (1.0f / 32.0f);
    sc = expf(fminf(fmaxf(sc, -10.0f), 10.0f));
    atomicAdd(&A[((size_t)((b << 10) + d) << 10) + s], sc);
    atomicAdd(&G[((size_t)((b << 10) + d) << 6) + r], sc);
}

// per node: inv = 1/sum_r G[row,r]; Awv[row] = bf16([A*inv | G*inv])  (1088-wide)
__global__ void normalize(const float* __restrict__ A, const float* __restrict__ G,
                          unsigned short* __restrict__ Awv) {
    __shared__ float sInv;
    const int row = blockIdx.x, t = threadIdx.x;
    float v = 0.0f;
    if (t < 64) {
        v = G[(size_t)row * 64 + t];
        float s = v;
#pragma unroll
        for (int o = 1; o < 64; o <<= 1) s += __shfl_xor(s, o);
        if (t == 0) sInv = 1.0f / s;
    }
    __syncthreads();
    const float inv = sInv;
    const size_t obase = (size_t)row * LDA_WV;
    const float4 a = *(const float4*)(A + (size_t)row * 1024 + t * 4);
    ushort4 o;
    o.x = f2b(a.x * inv); o.y = f2b(a.y * inv); o.z = f2b(a.z * inv); o.w = f2b(a.w * inv);
    *(ushort4*)(Awv + obase + t * 4) = o;
    if (t < 16) {
        const float4 gq = *(const float4*)(G + (size_t)row * 64 + t * 4);
        ushort4 og;
        og.x = f2b(gq.x * inv); og.y = f2b(gq.y * inv);
        og.z = f2b(gq.z * inv); og.w = f2b(gq.w * inv);
        *(ushort4*)(Awv + obase + 1024 + t * 4) = og;
    }
}

// ---------------- launch ----------------
extern "C" void kernel_launch(void* const* d_in, const int* in_sizes, int n_in,
                              void* d_out, int out_size, void* d_ws, size_t ws_size,
                              hipStream_t stream) {
    const float* hidden  = (const float*)d_in[0];
    const float* rel_tbl = (const float*)d_in[1];
    const float* Wq = (const float*)d_in[2];
    const float* bq = (const float*)d_in[3];
    const float* Wk = (const float*)d_in[4];
    const float* Wv = (const float*)d_in[5];
    const float* Wo = (const float*)d_in[6];
    const float* bo = (const float*)d_in[7];
    const float* ln0_g = (const float*)d_in[8];
    const float* ln0_b = (const float*)d_in[9];
    const float* ln1_g = (const float*)d_in[10];
    const float* ln1_b = (const float*)d_in[11];
    const float* W1 = (const float*)d_in[12];
    const float* b1 = (const float*)d_in[13];
    const float* W2 = (const float*)d_in[14];
    const float* b2 = (const float*)d_in[15];
    const float* ln2_g = (const float*)d_in[16];
    const float* ln2_b = (const float*)d_in[17];
    const int* esrc = (const int*)d_in[18];
    const int* edst = (const int*)d_in[19];
    const int* erel = (const int*)d_in[20];
    float* out = (float*)d_out;

    // ws lifetime map (peak 121MB) — identical overlay to R12.
    char* ws = (char*)d_ws;
    const size_t MB = 1024 * 1024;
    unsigned short* Xn_b16  = (unsigned short*)(ws + 16 * MB);
    unsigned short* H1      = (unsigned short*)(ws + 0);
    unsigned short* Wqkv_t  = (unsigned short*)(ws + 24 * MB);
    unsigned short* Wo_t    = (unsigned short*)(ws + 30 * MB);
    unsigned short* W1_t    = (unsigned short*)(ws + 32 * MB);
    unsigned short* W2_t    = (unsigned short*)(ws + 40 * MB);
    unsigned short* relbPad = (unsigned short*)(ws + 48 * MB);
    float*          bqkv    = (float*)(ws + 48 * MB + 512 * 1024);
    unsigned short* QKV     = (unsigned short*)(ws + 49 * MB);
    unsigned short* Awv     = (unsigned short*)(ws + 49 * MB);
    unsigned short* Qw2H    = (unsigned short*)(ws + 49 * MB);
    unsigned short* PwoH    = (unsigned short*)(ws + 66 * MB);
    unsigned short* SxH     = (unsigned short*)(ws + 73 * MB);
    unsigned short* Bwvp    = (unsigned short*)(ws + 92 * MB);
    float*          Amat    = (float*)(ws + 101 * MB);
    float*          Gmat    = (float*)(ws + 117 * MB);
    unsigned short* Out_b16 = (unsigned short*)(ws + 113 * MB);

    const size_t PSTRIDE_H = 4u * 1024 * 1024;   // 8MB bf16 partial, in ushorts
    const dim3 blk(256);
    const dim3 blk512(512);

    // ---- fused prep ----
    prep_all<<<17996, blk, 0, stream>>>(Wq, Wk, Wv, Wo, W1, W2, rel_tbl, bq,
                                        hidden, ln0_g, ln0_b,
                                        Wqkv_t, Wo_t, W1_t, W2_t, relbPad, bqkv,
                                        Xn_b16, Amat);
    // ---- QKV GEMM (256² pipelined: M=4096,N=3072,K=1024 -> 192 blocks) ----
    gemm256<false, false><<<dim3(192), blk512, 0, stream>>>(
        Xn_b16, 1024, Wqkv_t, 1024, bqkv, QKV, 0, 3072, 1024, 12);
    // ---- S_ext GEMM + W' GEMM (merged, 128² core) ----
    sext_w<<<864, blk, 0, stream>>>(QKV, relbPad, Wo_t, SxH, Bwvp, 512);
    // ---- scatter scores into pre-zeroed A,G ----
    edge_scatter<<<512, blk, 0, stream>>>(SxH, esrc, edst, erel, Amat, Gmat);
    // ---- normalize -> Awv [4096,1088] ----
    normalize<<<M_ROWS, blk, 0, stream>>>(Amat, Gmat, Awv);
    // ---- wv': attention out = Awv @ Bwv'^T + bo (asym split-K=2 -> PwoH, 128² core) ----
    gemm_wv_splitk<<<dim3(256, 1, 2), blk, 0, stream>>>(Awv, Bwvp, bo, PwoH, PSTRIDE_H);
    // ---- LN1: LN(Xn + Pwo) -> Out_b16 ----
    ln_kernel<false, 2><<<M_ROWS, blk, 0, stream>>>(Xn_b16, PwoH, PSTRIDE_H, ln1_g, ln1_b,
                                                    Out_b16, nullptr, nullptr);
    // ---- FFN1 (256² pipelined: M=4096,N=4096,K=1024 -> 256 blocks) ----
    gemm256<true, false><<<dim3(256), blk512, 0, stream>>>(
        Out_b16, 1024, W1_t, 1024, b1, H1, 0, 4096, 1024, 16);
    // ---- W2 (256² pipelined split-K=4: 4x M=4096,N=1024,Kc=1024 -> 256 blocks) ----
    gemm256<false, true><<<dim3(64, 1, 4), blk512, 0, stream>>>(
        H1, 4096, W2_t, 4096, b2, Qw2H, PSTRIDE_H, 1024, 1024, 4);
    // ---- LN2(out + sum Qw2) + elu + residual ----
    ln_kernel<true, 4><<<M_ROWS, blk, 0, stream>>>(Out_b16, Qw2H, PSTRIDE_H, ln2_g, ln2_b,
                                                   nullptr, hidden, out);
    (void)in_sizes; (void)n_in; (void)out_size; (void)ws_size;
}

// Round 7
// 348.186 us; speedup vs baseline: 1.7285x; 1.7285x over previous
//
#include <hip/hip_runtime.h>
#include <hip/hip_bf16.h>

#define B_SZ 4
#define L_SEQ 1024
#define D_MODEL 1024
#define DF_FF 4096
#define E_PER_B 32768
#define R_REL 64
#define M_ROWS (B_SZ * L_SEQ)   // 4096

typedef __attribute__((ext_vector_type(8))) short bf16x8;
typedef __attribute__((ext_vector_type(4))) float f32x4;

__device__ inline float b2f(unsigned short u) {
    union { unsigned int i; float f; } x; x.i = ((unsigned int)u) << 16; return x.f;
}
__device__ inline unsigned short f2b(float f) {
    union { float f; unsigned int u; } x; x.f = f;
    unsigned int r = x.u + 0x7FFFu + ((x.u >> 16) & 1u);
    return (unsigned short)(r >> 16);
}

#define GLOBAL_CAST(p) ((const __attribute__((address_space(1))) void*)(p))
#define LDS_CAST(p)    ((__attribute__((address_space(3))) void*)(p))

#define BT_QKV (1024u * 3072u)           // per-batch QKV stride
#define SEXT_M 1152                      // S_ext rows per batch: 1024 src + 128 relPad
#define LDA_WV 1088                      // Awv K width: 1024 (A) + 64 (G)
#define LDB_WVP 1152                     // Bwv' row stride (K padded to 18*64)
#define BT_WVP (1024u * 1152u)           // per-batch Bwv' stride

// ---------------- fused prep: weights + relPad + bias + LN0(bf16) + zero(A|G) ----------------
__global__ void prep_all(const float* __restrict__ Wq, const float* __restrict__ Wk,
                         const float* __restrict__ Wv, const float* __restrict__ Wo,
                         const float* __restrict__ W1, const float* __restrict__ W2,
                         const float* __restrict__ rel, const float* __restrict__ bq,
                         const float* __restrict__ hidden,
                         const float* __restrict__ ln0_g, const float* __restrict__ ln0_b,
                         unsigned short* __restrict__ Wqkv_t, unsigned short* __restrict__ Wo_t,
                         unsigned short* __restrict__ W1_t, unsigned short* __restrict__ W2_t,
                         unsigned short* __restrict__ relbPad,
                         float* __restrict__ bqkv,
                         unsigned short* __restrict__ Xn_b16,
                         float* __restrict__ zeroReg) {
    __shared__ float tile[32][33];
    __shared__ float sb1[4], sb2[4];
    const int id = blockIdx.x, tid = threadIdx.x;
    if (id < 12288) {
        const float* src; unsigned short* dst; int K, N, x, y;
        if (id < 4096) {
            const int seg = id >> 10, t = id & 1023;
            K = 1024; N = 1024; x = t & 31; y = t >> 5;
            src = (seg == 0) ? Wq : (seg == 1) ? Wk : (seg == 2) ? Wv : Wo;
            dst = (seg == 3) ? Wo_t : (Wqkv_t + (size_t)seg * 1048576);
        } else if (id < 8192) {
            const int t = id - 4096; K = 1024; N = 4096; x = t & 127; y = t >> 7;
            src = W1; dst = W1_t;
        } else {
            const int t = id - 8192; K = 4096; N = 1024; x = t & 31; y = t >> 5;
            src = W2; dst = W2_t;
        }
        const int n0 = x * 32, k0 = y * 32, tx = tid & 31, ty = tid >> 5;
#pragma unroll
        for (int r = 0; r < 32; r += 8)
            tile[ty + r][tx] = src[(size_t)(k0 + ty + r) * N + (n0 + tx)];
        __syncthreads();
#pragma unroll
        for (int r = 0; r < 32; r += 8)
            dst[(size_t)(n0 + ty + r) * K + (k0 + tx)] = f2b(tile[tx][ty + r]);
    } else if (id < 12800) {
        const int i = (id - 12288) * 256 + tid;            // 131072
        relbPad[i] = (i < 65536) ? f2b(rel[i]) : (unsigned short)0;
    } else if (id < 12812) {
        const int i = (id - 12800) * 256 + tid;            // 3072
        bqkv[i] = (i < 1024) ? bq[i] : 0.0f;
    } else if (id < 16908) {
        // LN0 row -> bf16
        const int row = id - 12812, t = tid;
        const size_t base = (size_t)row * 1024 + t * 4;
        float4 xv = *(const float4*)(hidden + base);
        float x0 = xv.x, x1 = xv.y, x2 = xv.z, x3 = xv.w;
        float s = x0 + x1 + x2 + x3;
#pragma unroll
        for (int o = 32; o > 0; o >>= 1) s += __shfl_down(s, o);
        if ((t & 63) == 0) sb1[t >> 6] = s;
        __syncthreads();
        const float mu = (sb1[0] + sb1[1] + sb1[2] + sb1[3]) * (1.0f / 1024.0f);
        const float d0 = x0 - mu, d1 = x1 - mu, d2 = x2 - mu, d3 = x3 - mu;
        float s2 = d0 * d0 + d1 * d1 + d2 * d2 + d3 * d3;
#pragma unroll
        for (int o = 32; o > 0; o >>= 1) s2 += __shfl_down(s2, o);
        if ((t & 63) == 0) sb2[t >> 6] = s2;
        __syncthreads();
        const float var = (sb2[0] + sb2[1] + sb2[2] + sb2[3]) * (1.0f / 1024.0f);
        const float rstd = rsqrtf(var + 1e-6f);
        const float4 gv = *(const float4*)(ln0_g + t * 4);
        const float4 bv = *(const float4*)(ln0_b + t * 4);
        ushort4 ob;
        ob.x = f2b(d0 * rstd * gv.x + bv.x);
        ob.y = f2b(d1 * rstd * gv.y + bv.y);
        ob.z = f2b(d2 * rstd * gv.z + bv.z);
        ob.w = f2b(d3 * rstd * gv.w + bv.w);
        *(ushort4*)(Xn_b16 + base) = ob;
    } else {
        const size_t base = (size_t)(id - 16908) * 4096 + tid * 4;
        const float4 z4 = make_float4(0.f, 0.f, 0.f, 0.f);
#pragma unroll
        for (int j = 0; j < 4; j++)
            *(float4*)(zeroReg + base + j * 1024) = z4;
    }
}

// 1D XCD swizzle: XCD = linear_id % 8; group all tile_n of a tile_m on one XCD.
__device__ inline void tile_swizzle(int id, int ntn, int& tm, int& tn) {
    tm = ((id & 7) + ((id >> 3) / ntn) * 8) * 128;
    tn = ((id >> 3) % ntn) * 128;
}
__device__ inline void tsw256(int id, int ntn, int& tm, int& tn) {
    tm = ((id & 7) + ((id >> 3) / ntn) * 8) * 256;
    tn = ((id >> 3) % ntn) * 256;
}

// ---------------- GEMM: 16x16x32 MFMA core (known-good: 0 LDS conflicts) ----------------
#define GEMM_BODY(GA, LDA_, GB, LDB_, KLEN)                                                 \
    f32x4 acc[4][4];                                                                        \
    _Pragma("unroll") for (int i = 0; i < 4; i++)                                           \
        _Pragma("unroll") for (int j = 0; j < 4; j++) acc[i][j] = (f32x4)0.0f;              \
    for (int k0 = 0; k0 < (KLEN); k0 += 64) {                                               \
        __syncthreads();                                                                    \
        _Pragma("unroll") for (int r = 0; r < 4; ++r) {                                     \
            __builtin_amdgcn_global_load_lds(GLOBAL_CAST((GA) + (size_t)r * 8 * (LDA_)),    \
                LDS_CAST(&lA[(wave * 32 + r * 8) * 64]), 16, 0, 0);                         \
            __builtin_amdgcn_global_load_lds(GLOBAL_CAST((GB) + (size_t)r * 8 * (LDB_)),    \
                LDS_CAST(&lB[(wave * 32 + r * 8) * 64]), 16, 0, 0);                         \
        }                                                                                   \
        (GA) += 64; (GB) += 64;                                                             \
        __builtin_amdgcn_s_waitcnt(0);                                                      \
        __syncthreads();                                                                    \
        _Pragma("unroll") for (int kk = 0; kk < 2; ++kk) {                                  \
            const int cb = kk * 4 + quad;                                                   \
            bf16x8 af[4], bf[4];                                                            \
            _Pragma("unroll") for (int i = 0; i < 4; i++) {                                 \
                const int ra = wm + i * 16 + l16;                                           \
                af[i] = *(const bf16x8*)&lA[ra * 64 + ((cb ^ (ra & 7)) * 8)];               \
                const int rb = wn + i * 16 + l16;                                           \
                bf[i] = *(const bf16x8*)&lB[rb * 64 + ((cb ^ (rb & 7)) * 8)];               \
            }                                                                               \
            _Pragma("unroll") for (int mi = 0; mi < 4; mi++)                                \
                _Pragma("unroll") for (int ni = 0; ni < 4; ni++)                            \
                    acc[mi][ni] = __builtin_amdgcn_mfma_f32_16x16x32_bf16(                  \
                        af[mi], bf[ni], acc[mi][ni], 0, 0, 0);                              \
        }                                                                                   \
    }

// ================= 256x256 pipelined GEMM, reduced-register fragment plan ==================
// 512 thr = 8 waves (2M x 4N); per-wave C = 128x64; BK=64; LDS = 128KB (2buf x (A+B) x 32KB).
// 4 C-quadrant phases per K-tile, snake (Q0,N0)->(Q0,N1)->(Q1,N1)->(Q1,N0).
// KEY: B frags depend only on (buf,QN) -> read ONCE per K-tile (8 reads), reused at 2 phases.
// Slots: af (single, 32 regs) read IN-phase at P1/P3/P5/P7 with lgkm(0);
//        b0=B[N0], b1=B[N1] (16 regs each) reloaded immediately AFTER their last-use MFMA
//        (end of P3/P4/P7/P8) -> >=1 phase+barrier of flight, retired by next lgkm(0).
// Register budget: 128 acc + 64 frag + addr ~= 220 < 256 cap (8-wave block => 2 waves/SIMD).
// Stage calendar + VM4@P3/P7 + prologue identical to the R6-verified kernel. WAR safety:
// reads happen same-or-later than R6's positions, so every stage's safety margin only grows.
#define ST_Aq(bufc, QM, kt) { \
    _Pragma("unroll") for (int j_ = 0; j_ < 2; j_++) { \
        const int u_ = j_ * 8 + wv; \
        const int lr_ = ((u_ >> 3) * 128) + (QM) * 64 + ((u_ & 7) * 8); \
        __builtin_amdgcn_global_load_lds(GLOBAL_CAST(Ag + (size_t)lr_ * lda + (kt) * 64), \
            LDS_CAST(&ls[bufc][0][lr_ * 64]), 16, 0, 0); } }
#define ST_Bq(bufc, QN, kt) { \
    _Pragma("unroll") for (int j_ = 0; j_ < 2; j_++) { \
        const int u_ = j_ * 8 + wv; \
        const int lr_ = ((u_ >> 2) * 64) + (QN) * 32 + ((u_ & 3) * 8); \
        __builtin_amdgcn_global_load_lds(GLOBAL_CAST(Bg + (size_t)lr_ * ldb + (kt) * 64), \
            LDS_CAST(&ls[bufc][1][lr_ * 64]), 16, 0, 0); } }

#define RD_Af(bufc, QM) { \
    _Pragma("unroll") for (int m4_ = 0; m4_ < 4; m4_++) \
        _Pragma("unroll") for (int kk_ = 0; kk_ < 2; kk_++) \
            af[m4_][kk_] = *(const bf16x8*)&ls[bufc][0][ \
                (wm * 128 + (QM) * 64 + m4_ * 16 + l16) * 64 + (((kk_ * 4 + quad) ^ (l16 & 7)) * 8)]; }
#define RD_Bs(SLOT, bufc, QN) { \
    _Pragma("unroll") for (int n2_ = 0; n2_ < 2; n2_++) \
        _Pragma("unroll") for (int kk_ = 0; kk_ < 2; kk_++) \
            SLOT[n2_][kk_] = *(const bf16x8*)&ls[bufc][1][ \
                (wc * 64 + (QN) * 32 + n2_ * 16 + l16) * 64 + (((kk_ * 4 + quad) ^ (l16 & 7)) * 8)]; }

#define VM4 asm volatile("s_waitcnt vmcnt(4)" ::: "memory");
#define VM0 asm volatile("s_waitcnt vmcnt(0)" ::: "memory");

#define MMCL(QM, QN, BS) \
    __builtin_amdgcn_s_setprio(1); \
    _Pragma("unroll") for (int m4_ = 0; m4_ < 4; m4_++) \
        _Pragma("unroll") for (int n2_ = 0; n2_ < 2; n2_++) \
            _Pragma("unroll") for (int kk_ = 0; kk_ < 2; kk_++) \
                acc[(QM) * 4 + m4_][(QN) * 2 + n2_] = __builtin_amdgcn_mfma_f32_16x16x32_bf16( \
                    af[m4_][kk_], BS[n2_][kk_], acc[(QM) * 4 + m4_][(QN) * 2 + n2_], 0, 0, 0); \
    __builtin_amdgcn_s_setprio(0);

// phase with in-phase A read (exposed lgkm) ; phase with all frags held (no LDS wait)
#define PH_R(bufc, QM, QN, BS, STMT, POST) { \
    STMT; \
    RD_Af(bufc, QM) \
    asm volatile("s_waitcnt lgkmcnt(0)" ::: "memory"); \
    __builtin_amdgcn_sched_barrier(0); \
    MMCL(QM, QN, BS) \
    POST; \
    __builtin_amdgcn_s_barrier(); }
#define PH_H(bufc, QM, QN, BS, STMT, POST) { \
    STMT; \
    __builtin_amdgcn_sched_barrier(0); \
    MMCL(QM, QN, BS) \
    POST; \
    __builtin_amdgcn_s_barrier(); }

template<bool RELU, bool SPLITK>
__global__ __launch_bounds__(512, 2)
void gemm256(const unsigned short* __restrict__ A, int lda,
             const unsigned short* __restrict__ Bt, int ldb,
             const float* __restrict__ bias,
             unsigned short* __restrict__ C, size_t pstride,
             int N, int Kc, int ntn) {
    __shared__ unsigned short ls[2][2][16384];   // [buf][A/B][256 rows * 64]
    int tile_m, tile_n;
    tsw256(blockIdx.x, ntn, tile_m, tile_n);
    const int t = threadIdx.x;
    const int wv = t >> 6, lane = t & 63;
    const int wm = wv >> 2;                 // wave m-group 0..1 (128 rows)
    const int wc = wv & 3;                  // wave n-group 0..3 (64 cols)
    const int quad = lane >> 4, l16 = lane & 15;
    const int srow8 = lane >> 3;
    const int schunk = ((lane & 7) ^ srow8) * 8;
    const int z = SPLITK ? blockIdx.z : 0;
    const int kofs = z * Kc;

    const unsigned short* Ag = A + (size_t)(tile_m + srow8) * lda + kofs + schunk;
    const unsigned short* Bg = Bt + (size_t)(tile_n + srow8) * ldb + kofs + schunk;

    f32x4 acc[8][4];
#pragma unroll
    for (int i = 0; i < 8; i++)
#pragma unroll
        for (int j = 0; j < 4; j++) acc[i][j] = (f32x4)0.0f;
    bf16x8 af[4][2], b0f[2][2], b1f[2][2];

    // prologue: tile0 full -> buf0 (8 loads); tile1 A0,B1,A1 -> buf1 (6 loads; B0 at P1)
    ST_Aq(0, 0, 0) ST_Aq(0, 1, 0) ST_Bq(0, 0, 0) ST_Bq(0, 1, 0)
    ST_Aq(1, 0, 1) ST_Bq(1, 1, 1) ST_Aq(1, 1, 1)
    asm volatile("s_waitcnt vmcnt(6)" ::: "memory");   // tile0 complete
    __builtin_amdgcn_s_barrier();
    RD_Bs(b0f, 0, 0) RD_Bs(b1f, 0, 1)    // tile0 B pair; retired by P1's lgkm(0)

    const int NI = Kc >> 7;              // 2 K-tiles per iteration (Kc % 128 == 0)
    for (int it = 0; it < NI - 1; ++it) {
        const int t1 = 2 * it + 1, s0 = 2 * it + 2, s1 = 2 * it + 3;
        PH_R(0, 0, 0, b0f, ST_Bq(1, 0, t1), )                          // P1
        PH_H(0, 0, 1, b1f, ST_Aq(0, 0, s0), )                          // P2
        PH_R(0, 1, 1, b1f, ST_Bq(0, 1, s0), VM4 RD_Bs(b1f, 1, 1))      // P3
        PH_H(0, 1, 0, b0f, ST_Aq(0, 1, s0), RD_Bs(b0f, 1, 0))          // P4
        PH_R(1, 0, 0, b0f, ST_Bq(0, 0, s0), )                          // P5
        PH_H(1, 0, 1, b1f, ST_Aq(1, 0, s1), )                          // P6
        PH_R(1, 1, 1, b1f, ST_Bq(1, 1, s1), VM4 RD_Bs(b1f, 0, 1))      // P7
        PH_H(1, 1, 0, b0f, ST_Aq(1, 1, s1), RD_Bs(b0f, 0, 0))          // P8
    }
    {   // final iteration: only tile(2NI-1).B0 left to stage; drain at P3
        const int t1 = 2 * NI - 1;
        PH_R(0, 0, 0, b0f, ST_Bq(1, 0, t1), )
        PH_H(0, 0, 1, b1f, , )
        PH_R(0, 1, 1, b1f, , VM0 RD_Bs(b1f, 1, 1))
        PH_H(0, 1, 0, b0f, , RD_Bs(b0f, 1, 0))
        PH_R(1, 0, 0, b0f, , )
        PH_H(1, 0, 1, b1f, , )
        PH_R(1, 1, 1, b1f, , )
        PH_H(1, 1, 0, b0f, , )
    }

    unsigned short* Co = C + (SPLITK ? (size_t)z * pstride : 0);
#pragma unroll
    for (int mi = 0; mi < 8; mi++) {
#pragma unroll
        for (int ni = 0; ni < 4; ni++) {
            const int col = tile_n + wc * 64 + ni * 16 + l16;
            const float bv = (SPLITK && z != 0) ? 0.0f : bias[col];
#pragma unroll
            for (int r = 0; r < 4; r++) {
                const int row = tile_m + wm * 128 + mi * 16 + quad * 4 + r;
                float v = acc[mi][ni][r] + bv;
                if (RELU) v = fmaxf(v, 0.0f);
                Co[(size_t)row * N + col] = f2b(v);
            }
        }
    }
}

// ---------------- S_ext GEMM + W' GEMM, merged (both depend on QKV + weights only) ----------------
__global__ __launch_bounds__(256, 4)
void sext_w(const unsigned short* __restrict__ QKV,
            const unsigned short* __restrict__ relPad,
            const unsigned short* __restrict__ Wo_t,
            unsigned short* __restrict__ Pbase,
            unsigned short* __restrict__ Bwvp, int Kc) {
    __shared__ unsigned short lA[128 * 64];
    __shared__ unsigned short lB[128 * 64];
    const int id = blockIdx.x, t = threadIdx.x;
    const int wave = t >> 6, lane = t & 63;
    const int wm = (wave >> 1) * 64, wn = (wave & 1) * 64;
    const int quad = lane >> 4, l16 = lane & 15;
    const int srow = lane >> 3;
    const int schunk = ((lane & 7) ^ srow) * 8;

    if (id >= 576) {   // ---- W' segment ----
        const int t2 = id - 576;
        const int b = t2 / 72, rem = t2 % 72;
        const int tile_m = (rem / 9) * 128;          // e
        const int tile_n = (rem % 9) * 128;          // s | 1024+r
        const unsigned short* gA = Wo_t + (size_t)(tile_m + wave * 32 + srow) * 1024 + schunk;
        const int brow = tile_n + wave * 32 + srow;
        const unsigned short* gB;
        size_t ldb;
        if (tile_n < 1024) {                          // V rows, natural layout
            gB = QKV + (size_t)b * BT_QKV + (size_t)brow * 3072 + 2048 + schunk;
            ldb = 3072;
        } else {                                      // relPad rows
            gB = relPad + (size_t)(brow - 1024) * 1024 + schunk;
            ldb = 1024;
        }
        GEMM_BODY(gA, 1024, gB, ldb, 1024)
        unsigned short* P = Bwvp + (size_t)b * BT_WVP;
#pragma unroll
        for (int mi = 0; mi < 4; mi++) {
#pragma unroll
            for (int ni = 0; ni < 4; ni++) {
                const int col = tile_n + wn + ni * 16 + l16;
#pragma unroll
                for (int r = 0; r < 4; r++) {
                    const int row = tile_m + wm + mi * 16 + quad * 4 + r;
                    P[(size_t)row * LDB_WVP + col] = f2b(acc[mi][ni][r]);
                }
            }
        }
        return;
    }

    // ---- sext segment ----
    const int bx = id % 72, b = (id / 72) & 3, z = id / 288;
    const int tile_m = (bx >> 3) * 128;
    const int tile_n = (bx & 7) * 128;
    const int kofs = z * Kc;
    const int arow = tile_m + wave * 32 + srow;
    const unsigned short* gA;
    size_t lda;
    if (tile_m < 1024) {   // K rows
        gA = QKV + (size_t)b * BT_QKV + (size_t)arow * 3072 + 1024 + kofs + schunk;
        lda = 3072;
    } else {               // relPad rows
        gA = relPad + (size_t)(arow - 1024) * 1024 + kofs + schunk;
        lda = 1024;
    }
    const unsigned short* gB = QKV + (size_t)b * BT_QKV
                                   + (size_t)(tile_n + wave * 32 + srow) * 3072 + kofs + schunk;
    GEMM_BODY(gA, lda, gB, 3072, Kc)
    unsigned short* P = Pbase + ((size_t)z * B_SZ + b) * (SEXT_M * 1024);
#pragma unroll
    for (int mi = 0; mi < 4; mi++) {
#pragma unroll
        for (int ni = 0; ni < 4; ni++) {
            const int col = tile_n + wn + ni * 16 + l16;
#pragma unroll
            for (int r = 0; r < 4; r++) {
                const int row = tile_m + wm + mi * 16 + quad * 4 + r;
                P[(size_t)row * 1024 + col] = f2b(acc[mi][ni][r]);
            }
        }
    }
}

// ---------------- wv' GEMM: attention-out = Awv @ Bwv'^T + bo, asymmetric split-K=2 ----------------
__global__ __launch_bounds__(256, 4)
void gemm_wv_splitk(const unsigned short* __restrict__ A,
                    const unsigned short* __restrict__ Bt,
                    const float* __restrict__ bias,
                    unsigned short* __restrict__ Pbase, size_t pstride) {
    __shared__ unsigned short lA[128 * 64];
    __shared__ unsigned short lB[128 * 64];
    int tile_m, tile_n;
    tile_swizzle(blockIdx.x, 8, tile_m, tile_n);
    const int z = blockIdx.z;
    const int kofs = z * 576;
    const int Kc = z ? 512 : 576;
    const int t = threadIdx.x;
    const int wave = t >> 6, lane = t & 63;
    const int wm = (wave >> 1) * 64, wn = (wave & 1) * 64;
    const int quad = lane >> 4, l16 = lane & 15;
    const int srow = lane >> 3;
    const int schunk = ((lane & 7) ^ srow) * 8;
    const unsigned short* gA = A + (size_t)(tile_m + wave * 32 + srow) * LDA_WV + kofs + schunk;
    const unsigned short* gB = Bt + (size_t)(tile_m >> 10) * BT_WVP
                                  + (size_t)(tile_n + wave * 32 + srow) * LDB_WVP + kofs + schunk;
    GEMM_BODY(gA, LDA_WV, gB, LDB_WVP, Kc)
    unsigned short* P = Pbase + (size_t)z * pstride;
#pragma unroll
    for (int mi = 0; mi < 4; mi++) {
#pragma unroll
        for (int ni = 0; ni < 4; ni++) {
            const int col = tile_n + wn + ni * 16 + l16;
            const float bv = (z == 0) ? bias[col] : 0.0f;
#pragma unroll
            for (int r = 0; r < 4; r++) {
                const int row = tile_m + wm + mi * 16 + quad * 4 + r;
                P[(size_t)row * 1024 + col] = f2b(acc[mi][ni][r] + bv);
            }
        }
    }
}

// ---------------- LayerNorm family (bf16 X + bf16 partials) ----------------
template<bool FINAL, int NR>
__global__ void ln_kernel(const unsigned short* __restrict__ Xb,
                          const unsigned short* __restrict__ Rbase, size_t rstride,
                          const float* __restrict__ g, const float* __restrict__ be,
                          unsigned short* __restrict__ ob16,
                          const float* __restrict__ hidden, float* __restrict__ fout) {
    __shared__ float sb1[4], sb2[4];
    const int row = blockIdx.x, t = threadIdx.x;
    const size_t base = (size_t)row * 1024 + t * 4;

    ushort4 xv = *(const ushort4*)(Xb + base);
    float x0 = b2f(xv.x), x1 = b2f(xv.y), x2 = b2f(xv.z), x3 = b2f(xv.w);
#pragma unroll
    for (int r = 0; r < NR; r++) {
        ushort4 rv = *(const ushort4*)(Rbase + r * rstride + base);
        x0 += b2f(rv.x); x1 += b2f(rv.y); x2 += b2f(rv.z); x3 += b2f(rv.w);
    }
    float s = x0 + x1 + x2 + x3;
#pragma unroll
    for (int o = 32; o > 0; o >>= 1) s += __shfl_down(s, o);
    if ((t & 63) == 0) sb1[t >> 6] = s;
    __syncthreads();
    const float mu = (sb1[0] + sb1[1] + sb1[2] + sb1[3]) * (1.0f / 1024.0f);

    const float d0 = x0 - mu, d1 = x1 - mu, d2 = x2 - mu, d3 = x3 - mu;
    float s2 = d0 * d0 + d1 * d1 + d2 * d2 + d3 * d3;
#pragma unroll
    for (int o = 32; o > 0; o >>= 1) s2 += __shfl_down(s2, o);
    if ((t & 63) == 0) sb2[t >> 6] = s2;
    __syncthreads();
    const float var = (sb2[0] + sb2[1] + sb2[2] + sb2[3]) * (1.0f / 1024.0f);
    const float rstd = rsqrtf(var + 1e-6f);

    const float4 gv = *(const float4*)(g + t * 4);
    const float4 bv = *(const float4*)(be + t * 4);
    const float y0 = d0 * rstd * gv.x + bv.x;
    const float y1 = d1 * rstd * gv.y + bv.y;
    const float y2 = d2 * rstd * gv.z + bv.z;
    const float y3 = d3 * rstd * gv.w + bv.w;

    if (!FINAL) {
        ushort4 ob; ob.x = f2b(y0); ob.y = f2b(y1); ob.z = f2b(y2); ob.w = f2b(y3);
        *(ushort4*)(ob16 + base) = ob;
    } else {
        const float4 hv = *(const float4*)(hidden + base);
        const float e0 = y0 > 0.0f ? y0 : expm1f(y0);
        const float e1 = y1 > 0.0f ? y1 : expm1f(y1);
        const float e2 = y2 > 0.0f ? y2 : expm1f(y2);
        const float e3 = y3 > 0.0f ? y3 : expm1f(y3);
        float4 o; o.x = hv.x + e0; o.y = hv.y + e1; o.z = hv.z + e2; o.w = hv.w + e3;
        *(float4*)(fout + base) = o;
    }
}

// ---------------- dense edge phase ----------------
__global__ void edge_scatter(const unsigned short* __restrict__ S,
                             const int* __restrict__ src, const int* __restrict__ dst,
                             const int* __restrict__ rel,
                             float* __restrict__ A, float* __restrict__ G) {
    const size_t ZSTR = (size_t)B_SZ * SEXT_M * 1024;
    const int gg = blockIdx.x * 256 + threadIdx.x;   // B*E = 131072
    const int b = gg >> 15;
    const int s = src[gg], d = dst[gg], r = rel[gg];
    const size_t sbase = ((size_t)b * SEXT_M + s) * 1024 + d;
    const size_t tbase = ((size_t)b * SEXT_M + 1024 + r) * 1024 + d;
    const float sval = b2f(S[sbase]) + b2f(S[sbase + ZSTR]);
    const float tval = b2f(S[tbase]) + b2f(S[tbase + ZSTR]);
    float sc = (sval + tval) * (1.0f / 32.0f);
    sc = expf(fminf(fmaxf(sc, -10.0f), 10.0f));
    atomicAdd(&A[((size_t)((b << 10) + d) << 10) + s], sc);
    atomicAdd(&G[((size_t)((b << 10) + d) << 6) + r], sc);
}

// per node: inv = 1/sum_r G[row,r]; Awv[row] = bf16([A*inv | G*inv])  (1088-wide)
__global__ void normalize(const float* __restrict__ A, const float* __restrict__ G,
                          unsigned short* __restrict__ Awv) {
    __shared__ float sInv;
    const int row = blockIdx.x, t = threadIdx.x;
    float v = 0.0f;
    if (t < 64) {
        v = G[(size_t)row * 64 + t];
        float s = v;
#pragma unroll
        for (int o = 1; o < 64; o <<= 1) s += __shfl_xor(s, o);
        if (t == 0) sInv = 1.0f / s;
    }
    __syncthreads();
    const float inv = sInv;
    const size_t obase = (size_t)row * LDA_WV;
    const float4 a = *(const float4*)(A + (size_t)row * 1024 + t * 4);
    ushort4 o;
    o.x = f2b(a.x * inv); o.y = f2b(a.y * inv); o.z = f2b(a.z * inv); o.w = f2b(a.w * inv);
    *(ushort4*)(Awv + obase + t * 4) = o;
    if (t < 16) {
        const float4 gq = *(const float4*)(G + (size_t)row * 64 + t * 4);
        ushort4 og;
        og.x = f2b(gq.x * inv); og.y = f2b(gq.y * inv);
        og.z = f2b(gq.z * inv); og.w = f2b(gq.w * inv);
        *(ushort4*)(Awv + obase + 1024 + t * 4) = og;
    }
}

// ---------------- launch ----------------
extern "C" void kernel_launch(void* const* d_in, const int* in_sizes, int n_in,
                              void* d_out, int out_size, void* d_ws, size_t ws_size,
                              hipStream_t stream) {
    const float* hidden  = (const float*)d_in[0];
    const float* rel_tbl = (const float*)d_in[1];
    const float* Wq = (const float*)d_in[2];
    const float* bq = (const float*)d_in[3];
    const float* Wk = (const float*)d_in[4];
    const float* Wv = (const float*)d_in[5];
    const float* Wo = (const float*)d_in[6];
    const float* bo = (const float*)d_in[7];
    const float* ln0_g = (const float*)d_in[8];
    const float* ln0_b = (const float*)d_in[9];
    const float* ln1_g = (const float*)d_in[10];
    const float* ln1_b = (const float*)d_in[11];
    const float* W1 = (const float*)d_in[12];
    const float* b1 = (const float*)d_in[13];
    const float* W2 = (const float*)d_in[14];
    const float* b2 = (const float*)d_in[15];
    const float* ln2_g = (const float*)d_in[16];
    const float* ln2_b = (const float*)d_in[17];
    const int* esrc = (const int*)d_in[18];
    const int* edst = (const int*)d_in[19];
    const int* erel = (const int*)d_in[20];
    float* out = (float*)d_out;

    // ws lifetime map (peak 121MB) — identical overlay to R12.
    char* ws = (char*)d_ws;
    const size_t MB = 1024 * 1024;
    unsigned short* Xn_b16  = (unsigned short*)(ws + 16 * MB);
    unsigned short* H1      = (unsigned short*)(ws + 0);
    unsigned short* Wqkv_t  = (unsigned short*)(ws + 24 * MB);
    unsigned short* Wo_t    = (unsigned short*)(ws + 30 * MB);
    unsigned short* W1_t    = (unsigned short*)(ws + 32 * MB);
    unsigned short* W2_t    = (unsigned short*)(ws + 40 * MB);
    unsigned short* relbPad = (unsigned short*)(ws + 48 * MB);
    float*          bqkv    = (float*)(ws + 48 * MB + 512 * 1024);
    unsigned short* QKV     = (unsigned short*)(ws + 49 * MB);
    unsigned short* Awv     = (unsigned short*)(ws + 49 * MB);
    unsigned short* Qw2H    = (unsigned short*)(ws + 49 * MB);
    unsigned short* PwoH    = (unsigned short*)(ws + 66 * MB);
    unsigned short* SxH     = (unsigned short*)(ws + 73 * MB);
    unsigned short* Bwvp    = (unsigned short*)(ws + 92 * MB);
    float*          Amat    = (float*)(ws + 101 * MB);
    float*          Gmat    = (float*)(ws + 117 * MB);
    unsigned short* Out_b16 = (unsigned short*)(ws + 113 * MB);

    const size_t PSTRIDE_H = 4u * 1024 * 1024;   // 8MB bf16 partial, in ushorts
    const dim3 blk(256);
    const dim3 blk512(512);

    // ---- fused prep ----
    prep_all<<<17996, blk, 0, stream>>>(Wq, Wk, Wv, Wo, W1, W2, rel_tbl, bq,
                                        hidden, ln0_g, ln0_b,
                                        Wqkv_t, Wo_t, W1_t, W2_t, relbPad, bqkv,
                                        Xn_b16, Amat);
    // ---- QKV GEMM (256² pipelined: M=4096,N=3072,K=1024 -> 192 blocks) ----
    gemm256<false, false><<<dim3(192), blk512, 0, stream>>>(
        Xn_b16, 1024, Wqkv_t, 1024, bqkv, QKV, 0, 3072, 1024, 12);
    // ---- S_ext GEMM + W' GEMM (merged, 128² core) ----
    sext_w<<<864, blk, 0, stream>>>(QKV, relbPad, Wo_t, SxH, Bwvp, 512);
    // ---- scatter scores into pre-zeroed A,G ----
    edge_scatter<<<512, blk, 0, stream>>>(SxH, esrc, edst, erel, Amat, Gmat);
    // ---- normalize -> Awv [4096,1088] ----
    normalize<<<M_ROWS, blk, 0, stream>>>(Amat, Gmat, Awv);
    // ---- wv': attention out = Awv @ Bwv'^T + bo (asym split-K=2 -> PwoH, 128² core) ----
    gemm_wv_splitk<<<dim3(256, 1, 2), blk, 0, stream>>>(Awv, Bwvp, bo, PwoH, PSTRIDE_H);
    // ---- LN1: LN(Xn + Pwo) -> Out_b16 ----
    ln_kernel<false, 2><<<M_ROWS, blk, 0, stream>>>(Xn_b16, PwoH, PSTRIDE_H, ln1_g, ln1_b,
                                                    Out_b16, nullptr, nullptr);
    // ---- FFN1 (256² pipelined: M=4096,N=4096,K=1024 -> 256 blocks) ----
    gemm256<true, false><<<dim3(256), blk512, 0, stream>>>(
        Out_b16, 1024, W1_t, 1024, b1, H1, 0, 4096, 1024, 16);
    // ---- W2 (256² pipelined split-K=4: 4x M=4096,N=1024,Kc=1024 -> 256 blocks) ----
    gemm256<false, true><<<dim3(64, 1, 4), blk512, 0, stream>>>(
        H1, 4096, W2_t, 4096, b2, Qw2H, PSTRIDE_H, 1024, 1024, 4);
    // ---- LN2(out + sum Qw2) + elu + residual ----
    ln_kernel<true, 4><<<M_ROWS, blk, 0, stream>>>(Out_b16, Qw2H, PSTRIDE_H, ln2_g, ln2_b,
                                                   nullptr, hidden, out);
    (void)in_sizes; (void)n_in; (void)out_size; (void)ws_size;
}

// Round 8
// 347.244 us; speedup vs baseline: 1.7332x; 1.0027x over previous
//
#include <hip/hip_runtime.h>
#include <hip/hip_bf16.h>

#define B_SZ 4
#define L_SEQ 1024
#define D_MODEL 1024
#define DF_FF 4096
#define E_PER_B 32768
#define R_REL 64
#define M_ROWS (B_SZ * L_SEQ)   // 4096

typedef __attribute__((ext_vector_type(8))) short bf16x8;
typedef __attribute__((ext_vector_type(4))) float f32x4;

__device__ inline float b2f(unsigned short u) {
    union { unsigned int i; float f; } x; x.i = ((unsigned int)u) << 16; return x.f;
}
__device__ inline unsigned short f2b(float f) {
    union { float f; unsigned int u; } x; x.f = f;
    unsigned int r = x.u + 0x7FFFu + ((x.u >> 16) & 1u);
    return (unsigned short)(r >> 16);
}

#define GLOBAL_CAST(p) ((const __attribute__((address_space(1))) void*)(p))
#define LDS_CAST(p)    ((__attribute__((address_space(3))) void*)(p))

#define BT_QKV (1024u * 3072u)           // per-batch QKV stride
#define SEXT_M 1152                      // S_ext rows per batch: 1024 src + 128 relPad
#define LDA_WV 1088                      // Awv K width: 1024 (A) + 64 (G)
#define LDB_WVP 1152                     // Bwv' row stride (K padded to 18*64)
#define BT_WVP (1024u * 1152u)           // per-batch Bwv' stride

// ---------------- fused prep: weights + relPad + bias + LN0(bf16) + zero(A|G) ----------------
__global__ void prep_all(const float* __restrict__ Wq, const float* __restrict__ Wk,
                         const float* __restrict__ Wv, const float* __restrict__ Wo,
                         const float* __restrict__ W1, const float* __restrict__ W2,
                         const float* __restrict__ rel, const float* __restrict__ bq,
                         const float* __restrict__ hidden,
                         const float* __restrict__ ln0_g, const float* __restrict__ ln0_b,
                         unsigned short* __restrict__ Wqkv_t, unsigned short* __restrict__ Wo_t,
                         unsigned short* __restrict__ W1_t, unsigned short* __restrict__ W2_t,
                         unsigned short* __restrict__ relbPad,
                         float* __restrict__ bqkv,
                         unsigned short* __restrict__ Xn_b16,
                         float* __restrict__ zeroReg) {
    __shared__ float tile[32][33];
    __shared__ float sb1[4], sb2[4];
    const int id = blockIdx.x, tid = threadIdx.x;
    if (id < 12288) {
        const float* src; unsigned short* dst; int K, N, x, y;
        if (id < 4096) {
            const int seg = id >> 10, t = id & 1023;
            K = 1024; N = 1024; x = t & 31; y = t >> 5;
            src = (seg == 0) ? Wq : (seg == 1) ? Wk : (seg == 2) ? Wv : Wo;
            dst = (seg == 3) ? Wo_t : (Wqkv_t + (size_t)seg * 1048576);
        } else if (id < 8192) {
            const int t = id - 4096; K = 1024; N = 4096; x = t & 127; y = t >> 7;
            src = W1; dst = W1_t;
        } else {
            const int t = id - 8192; K = 4096; N = 1024; x = t & 31; y = t >> 5;
            src = W2; dst = W2_t;
        }
        const int n0 = x * 32, k0 = y * 32, tx = tid & 31, ty = tid >> 5;
#pragma unroll
        for (int r = 0; r < 32; r += 8)
            tile[ty + r][tx] = src[(size_t)(k0 + ty + r) * N + (n0 + tx)];
        __syncthreads();
#pragma unroll
        for (int r = 0; r < 32; r += 8)
            dst[(size_t)(n0 + ty + r) * K + (k0 + tx)] = f2b(tile[tx][ty + r]);
    } else if (id < 12800) {
        const int i = (id - 12288) * 256 + tid;            // 131072
        relbPad[i] = (i < 65536) ? f2b(rel[i]) : (unsigned short)0;
    } else if (id < 12812) {
        const int i = (id - 12800) * 256 + tid;            // 3072
        bqkv[i] = (i < 1024) ? bq[i] : 0.0f;
    } else if (id < 16908) {
        // LN0 row -> bf16
        const int row = id - 12812, t = tid;
        const size_t base = (size_t)row * 1024 + t * 4;
        float4 xv = *(const float4*)(hidden + base);
        float x0 = xv.x, x1 = xv.y, x2 = xv.z, x3 = xv.w;
        float s = x0 + x1 + x2 + x3;
#pragma unroll
        for (int o = 32; o > 0; o >>= 1) s += __shfl_down(s, o);
        if ((t & 63) == 0) sb1[t >> 6] = s;
        __syncthreads();
        const float mu = (sb1[0] + sb1[1] + sb1[2] + sb1[3]) * (1.0f / 1024.0f);
        const float d0 = x0 - mu, d1 = x1 - mu, d2 = x2 - mu, d3 = x3 - mu;
        float s2 = d0 * d0 + d1 * d1 + d2 * d2 + d3 * d3;
#pragma unroll
        for (int o = 32; o > 0; o >>= 1) s2 += __shfl_down(s2, o);
        if ((t & 63) == 0) sb2[t >> 6] = s2;
        __syncthreads();
        const float var = (sb2[0] + sb2[1] + sb2[2] + sb2[3]) * (1.0f / 1024.0f);
        const float rstd = rsqrtf(var + 1e-6f);
        const float4 gv = *(const float4*)(ln0_g + t * 4);
        const float4 bv = *(const float4*)(ln0_b + t * 4);
        ushort4 ob;
        ob.x = f2b(d0 * rstd * gv.x + bv.x);
        ob.y = f2b(d1 * rstd * gv.y + bv.y);
        ob.z = f2b(d2 * rstd * gv.z + bv.z);
        ob.w = f2b(d3 * rstd * gv.w + bv.w);
        *(ushort4*)(Xn_b16 + base) = ob;
    } else {
        const size_t base = (size_t)(id - 16908) * 4096 + tid * 4;
        const float4 z4 = make_float4(0.f, 0.f, 0.f, 0.f);
#pragma unroll
        for (int j = 0; j < 4; j++)
            *(float4*)(zeroReg + base + j * 1024) = z4;
    }
}

// 1D XCD swizzle: XCD = linear_id % 8; group all tile_n of a tile_m on one XCD.
__device__ inline void tile_swizzle(int id, int ntn, int& tm, int& tn) {
    tm = ((id & 7) + ((id >> 3) / ntn) * 8) * 128;
    tn = ((id >> 3) % ntn) * 128;
}
__device__ inline void tsw256(int id, int ntn, int& tm, int& tn) {
    tm = ((id & 7) + ((id >> 3) / ntn) * 8) * 256;
    tn = ((id >> 3) % ntn) * 256;
}

// ---------------- GEMM: 16x16x32 MFMA core (known-good: 0 LDS conflicts) ----------------
#define GEMM_BODY(GA, LDA_, GB, LDB_, KLEN)                                                 \
    f32x4 acc[4][4];                                                                        \
    _Pragma("unroll") for (int i = 0; i < 4; i++)                                           \
        _Pragma("unroll") for (int j = 0; j < 4; j++) acc[i][j] = (f32x4)0.0f;              \
    for (int k0 = 0; k0 < (KLEN); k0 += 64) {                                               \
        __syncthreads();                                                                    \
        _Pragma("unroll") for (int r = 0; r < 4; ++r) {                                     \
            __builtin_amdgcn_global_load_lds(GLOBAL_CAST((GA) + (size_t)r * 8 * (LDA_)),    \
                LDS_CAST(&lA[(wave * 32 + r * 8) * 64]), 16, 0, 0);                         \
            __builtin_amdgcn_global_load_lds(GLOBAL_CAST((GB) + (size_t)r * 8 * (LDB_)),    \
                LDS_CAST(&lB[(wave * 32 + r * 8) * 64]), 16, 0, 0);                         \
        }                                                                                   \
        (GA) += 64; (GB) += 64;                                                             \
        __builtin_amdgcn_s_waitcnt(0);                                                      \
        __syncthreads();                                                                    \
        _Pragma("unroll") for (int kk = 0; kk < 2; ++kk) {                                  \
            const int cb = kk * 4 + quad;                                                   \
            bf16x8 af[4], bf[4];                                                            \
            _Pragma("unroll") for (int i = 0; i < 4; i++) {                                 \
                const int ra = wm + i * 16 + l16;                                           \
                af[i] = *(const bf16x8*)&lA[ra * 64 + ((cb ^ (ra & 7)) * 8)];               \
                const int rb = wn + i * 16 + l16;                                           \
                bf[i] = *(const bf16x8*)&lB[rb * 64 + ((cb ^ (rb & 7)) * 8)];               \
            }                                                                               \
            _Pragma("unroll") for (int mi = 0; mi < 4; mi++)                                \
                _Pragma("unroll") for (int ni = 0; ni < 4; ni++)                            \
                    acc[mi][ni] = __builtin_amdgcn_mfma_f32_16x16x32_bf16(                  \
                        af[mi], bf[ni], acc[mi][ni], 0, 0, 0);                              \
        }                                                                                   \
    }

// ================= 256x256 GEMM — m201-skeleton phases (2 barriers) + minimal LDS traffic ===
// 512 thr = 8 waves (2M x 4N); per-wave C = 128x64; BK=64; LDS = 128KB (2buf x (A+B) x 32KB).
// Phase skeleton (template-faithful): {STAGE; READS; [lgkm(8) if 12 reads]; barrier;
//   lgkm(0); sched_barrier; setprio(1); 16 MFMA; setprio(0); vmcnt(2); barrier}.
// Reads issued BEFORE barrier-1 -> per-wave lgkm(0)s retire in LDS-service order -> waves
// desync inside the MFMA window -> wave-A MFMA overlaps wave-B LDS service.
// 4 phases/K-tile, snake (Q0,N0)->(Q0,N1)->(Q1,N1)->(Q1,N0). Reads/K-tile/wave = 24 (min):
// P1: A[Q0](8)+B[N0](4); P2: B[N1](4); P3: A[Q1](8); P4: none. b0 used P1+P4, b1 P2+P3
// (reg-carry across barriers). Stages (1 ST = 2 loads/wave per phase): A0,B0,B1,A1 of tile
// t+1 during tile t. Uniform vmcnt(2) pre-barrier: any ST >=2 phases old is retired before
// the next phase's reads (cross-wave safe: every wave's vmcnt precedes its barrier arrival).
// WAR: each stage's region was last LDS-read >=1 lgkm-retire + >=1 barrier earlier.
#define ST_Aq(bufc, QM, kt) { \
    _Pragma("unroll") for (int j_ = 0; j_ < 2; j_++) { \
        const int u_ = j_ * 8 + wv; \
        const int lr_ = ((u_ >> 3) * 128) + (QM) * 64 + ((u_ & 7) * 8); \
        __builtin_amdgcn_global_load_lds(GLOBAL_CAST(Ag + (size_t)lr_ * lda + (kt) * 64), \
            LDS_CAST(&ls[bufc][0][lr_ * 64]), 16, 0, 0); } }
#define ST_Bq(bufc, QN, kt) { \
    _Pragma("unroll") for (int j_ = 0; j_ < 2; j_++) { \
        const int u_ = j_ * 8 + wv; \
        const int lr_ = ((u_ >> 2) * 64) + (QN) * 32 + ((u_ & 3) * 8); \
        __builtin_amdgcn_global_load_lds(GLOBAL_CAST(Bg + (size_t)lr_ * ldb + (kt) * 64), \
            LDS_CAST(&ls[bufc][1][lr_ * 64]), 16, 0, 0); } }

#define RD_Af(bufc, QM) { \
    _Pragma("unroll") for (int m4_ = 0; m4_ < 4; m4_++) \
        _Pragma("unroll") for (int kk_ = 0; kk_ < 2; kk_++) \
            af[m4_][kk_] = *(const bf16x8*)&ls[bufc][0][ \
                (wm * 128 + (QM) * 64 + m4_ * 16 + l16) * 64 + (((kk_ * 4 + quad) ^ (l16 & 7)) * 8)]; }
#define RD_Bs(SLOT, bufc, QN) { \
    _Pragma("unroll") for (int n2_ = 0; n2_ < 2; n2_++) \
        _Pragma("unroll") for (int kk_ = 0; kk_ < 2; kk_++) \
            SLOT[n2_][kk_] = *(const bf16x8*)&ls[bufc][1][ \
                (wc * 64 + (QN) * 32 + n2_ * 16 + l16) * 64 + (((kk_ * 4 + quad) ^ (l16 & 7)) * 8)]; }

#define VM2 asm volatile("s_waitcnt vmcnt(2)" ::: "memory");
#define VM0 asm volatile("s_waitcnt vmcnt(0)" ::: "memory");
#define LG8 asm volatile("s_waitcnt lgkmcnt(8)" ::: "memory");

#define MMCL(QM, QN, BS) \
    __builtin_amdgcn_s_setprio(1); \
    _Pragma("unroll") for (int m4_ = 0; m4_ < 4; m4_++) \
        _Pragma("unroll") for (int n2_ = 0; n2_ < 2; n2_++) \
            _Pragma("unroll") for (int kk_ = 0; kk_ < 2; kk_++) \
                acc[(QM) * 4 + m4_][(QN) * 2 + n2_] = __builtin_amdgcn_mfma_f32_16x16x32_bf16( \
                    af[m4_][kk_], BS[n2_][kk_], acc[(QM) * 4 + m4_][(QN) * 2 + n2_], 0, 0, 0); \
    __builtin_amdgcn_s_setprio(0);

#define PH2(STMT, READS, LGPRE, QM, QN, BS, VMW) { \
    STMT; \
    READS; \
    LGPRE; \
    __builtin_amdgcn_s_barrier(); \
    asm volatile("s_waitcnt lgkmcnt(0)" ::: "memory"); \
    __builtin_amdgcn_sched_barrier(0); \
    MMCL(QM, QN, BS) \
    VMW; \
    __builtin_amdgcn_s_barrier(); }

template<bool RELU, bool SPLITK>
__global__ __launch_bounds__(512, 2)
void gemm256(const unsigned short* __restrict__ A, int lda,
             const unsigned short* __restrict__ Bt, int ldb,
             const float* __restrict__ bias,
             unsigned short* __restrict__ C, size_t pstride,
             int N, int Kc, int ntn) {
    __shared__ unsigned short ls[2][2][16384];   // [buf][A/B][256 rows * 64]
    int tile_m, tile_n;
    tsw256(blockIdx.x, ntn, tile_m, tile_n);
    const int t = threadIdx.x;
    const int wv = t >> 6, lane = t & 63;
    const int wm = wv >> 2;                 // wave m-group 0..1 (128 rows)
    const int wc = wv & 3;                  // wave n-group 0..3 (64 cols)
    const int quad = lane >> 4, l16 = lane & 15;
    const int srow8 = lane >> 3;
    const int schunk = ((lane & 7) ^ srow8) * 8;
    const int z = SPLITK ? blockIdx.z : 0;
    const int kofs = z * Kc;

    const unsigned short* Ag = A + (size_t)(tile_m + srow8) * lda + kofs + schunk;
    const unsigned short* Bg = Bt + (size_t)(tile_n + srow8) * ldb + kofs + schunk;

    f32x4 acc[8][4];
#pragma unroll
    for (int i = 0; i < 8; i++)
#pragma unroll
        for (int j = 0; j < 4; j++) acc[i][j] = (f32x4)0.0f;
    bf16x8 af[4][2], b0f[2][2], b1f[2][2];

    // prologue: tile0 full -> buf0 (8 loads/wave), drain, barrier
    ST_Aq(0, 0, 0) ST_Bq(0, 0, 0) ST_Bq(0, 1, 0) ST_Aq(0, 1, 0)
    VM0
    __builtin_amdgcn_s_barrier();

    const int NT = Kc >> 6;              // K-tiles (Kc % 64 == 0; NT even not required)
    for (int tt = 0; tt < NT - 1; ++tt) {
        const int c = tt & 1, nb = c ^ 1;
        PH2(ST_Aq(nb, 0, tt + 1), RD_Af(c, 0) RD_Bs(b0f, c, 0), LG8, 0, 0, b0f, VM2)  // P1
        PH2(ST_Bq(nb, 0, tt + 1), RD_Bs(b1f, c, 1),            ,    0, 1, b1f, VM2)  // P2
        PH2(ST_Bq(nb, 1, tt + 1), RD_Af(c, 1),                 ,    1, 1, b1f, VM2)  // P3
        PH2(ST_Aq(nb, 1, tt + 1), ,                            ,    1, 0, b0f, VM2)  // P4
    }
    {   // final tile: no stages; VM0 at P1 covers the late-staged B1/A1 before their reads
        const int c = (NT - 1) & 1;
        PH2(, RD_Af(c, 0) RD_Bs(b0f, c, 0), LG8, 0, 0, b0f, VM0)
        PH2(, RD_Bs(b1f, c, 1),            ,    0, 1, b1f, )
        PH2(, RD_Af(c, 1),                 ,    1, 1, b1f, )
        PH2(, ,                            ,    1, 0, b0f, )
    }

    unsigned short* Co = C + (SPLITK ? (size_t)z * pstride : 0);
#pragma unroll
    for (int mi = 0; mi < 8; mi++) {
#pragma unroll
        for (int ni = 0; ni < 4; ni++) {
            const int col = tile_n + wc * 64 + ni * 16 + l16;
            const float bv = (SPLITK && z != 0) ? 0.0f : bias[col];
#pragma unroll
            for (int r = 0; r < 4; r++) {
                const int row = tile_m + wm * 128 + mi * 16 + quad * 4 + r;
                float v = acc[mi][ni][r] + bv;
                if (RELU) v = fmaxf(v, 0.0f);
                Co[(size_t)row * N + col] = f2b(v);
            }
        }
    }
}

// ---------------- S_ext GEMM + W' GEMM, merged (both depend on QKV + weights only) ----------------
__global__ __launch_bounds__(256, 4)
void sext_w(const unsigned short* __restrict__ QKV,
            const unsigned short* __restrict__ relPad,
            const unsigned short* __restrict__ Wo_t,
            unsigned short* __restrict__ Pbase,
            unsigned short* __restrict__ Bwvp, int Kc) {
    __shared__ unsigned short lA[128 * 64];
    __shared__ unsigned short lB[128 * 64];
    const int id = blockIdx.x, t = threadIdx.x;
    const int wave = t >> 6, lane = t & 63;
    const int wm = (wave >> 1) * 64, wn = (wave & 1) * 64;
    const int quad = lane >> 4, l16 = lane & 15;
    const int srow = lane >> 3;
    const int schunk = ((lane & 7) ^ srow) * 8;

    if (id >= 576) {   // ---- W' segment ----
        const int t2 = id - 576;
        const int b = t2 / 72, rem = t2 % 72;
        const int tile_m = (rem / 9) * 128;          // e
        const int tile_n = (rem % 9) * 128;          // s | 1024+r
        const unsigned short* gA = Wo_t + (size_t)(tile_m + wave * 32 + srow) * 1024 + schunk;
        const int brow = tile_n + wave * 32 + srow;
        const unsigned short* gB;
        size_t ldb;
        if (tile_n < 1024) {                          // V rows, natural layout
            gB = QKV + (size_t)b * BT_QKV + (size_t)brow * 3072 + 2048 + schunk;
            ldb = 3072;
        } else {                                      // relPad rows
            gB = relPad + (size_t)(brow - 1024) * 1024 + schunk;
            ldb = 1024;
        }
        GEMM_BODY(gA, 1024, gB, ldb, 1024)
        unsigned short* P = Bwvp + (size_t)b * BT_WVP;
#pragma unroll
        for (int mi = 0; mi < 4; mi++) {
#pragma unroll
            for (int ni = 0; ni < 4; ni++) {
                const int col = tile_n + wn + ni * 16 + l16;
#pragma unroll
                for (int r = 0; r < 4; r++) {
                    const int row = tile_m + wm + mi * 16 + quad * 4 + r;
                    P[(size_t)row * LDB_WVP + col] = f2b(acc[mi][ni][r]);
                }
            }
        }
        return;
    }

    // ---- sext segment ----
    const int bx = id % 72, b = (id / 72) & 3, z = id / 288;
    const int tile_m = (bx >> 3) * 128;
    const int tile_n = (bx & 7) * 128;
    const int kofs = z * Kc;
    const int arow = tile_m + wave * 32 + srow;
    const unsigned short* gA;
    size_t lda;
    if (tile_m < 1024) {   // K rows
        gA = QKV + (size_t)b * BT_QKV + (size_t)arow * 3072 + 1024 + kofs + schunk;
        lda = 3072;
    } else {               // relPad rows
        gA = relPad + (size_t)(arow - 1024) * 1024 + kofs + schunk;
        lda = 1024;
    }
    const unsigned short* gB = QKV + (size_t)b * BT_QKV
                                   + (size_t)(tile_n + wave * 32 + srow) * 3072 + kofs + schunk;
    GEMM_BODY(gA, lda, gB, 3072, Kc)
    unsigned short* P = Pbase + ((size_t)z * B_SZ + b) * (SEXT_M * 1024);
#pragma unroll
    for (int mi = 0; mi < 4; mi++) {
#pragma unroll
        for (int ni = 0; ni < 4; ni++) {
            const int col = tile_n + wn + ni * 16 + l16;
#pragma unroll
            for (int r = 0; r < 4; r++) {
                const int row = tile_m + wm + mi * 16 + quad * 4 + r;
                P[(size_t)row * 1024 + col] = f2b(acc[mi][ni][r]);
            }
        }
    }
}

// ---------------- wv' GEMM: attention-out = Awv @ Bwv'^T + bo, asymmetric split-K=2 ----------------
__global__ __launch_bounds__(256, 4)
void gemm_wv_splitk(const unsigned short* __restrict__ A,
                    const unsigned short* __restrict__ Bt,
                    const float* __restrict__ bias,
                    unsigned short* __restrict__ Pbase, size_t pstride) {
    __shared__ unsigned short lA[128 * 64];
    __shared__ unsigned short lB[128 * 64];
    int tile_m, tile_n;
    tile_swizzle(blockIdx.x, 8, tile_m, tile_n);
    const int z = blockIdx.z;
    const int kofs = z * 576;
    const int Kc = z ? 512 : 576;
    const int t = threadIdx.x;
    const int wave = t >> 6, lane = t & 63;
    const int wm = (wave >> 1) * 64, wn = (wave & 1) * 64;
    const int quad = lane >> 4, l16 = lane & 15;
    const int srow = lane >> 3;
    const int schunk = ((lane & 7) ^ srow) * 8;
    const unsigned short* gA = A + (size_t)(tile_m + wave * 32 + srow) * LDA_WV + kofs + schunk;
    const unsigned short* gB = Bt + (size_t)(tile_m >> 10) * BT_WVP
                                  + (size_t)(tile_n + wave * 32 + srow) * LDB_WVP + kofs + schunk;
    GEMM_BODY(gA, LDA_WV, gB, LDB_WVP, Kc)
    unsigned short* P = Pbase + (size_t)z * pstride;
#pragma unroll
    for (int mi = 0; mi < 4; mi++) {
#pragma unroll
        for (int ni = 0; ni < 4; ni++) {
            const int col = tile_n + wn + ni * 16 + l16;
            const float bv = (z == 0) ? bias[col] : 0.0f;
#pragma unroll
            for (int r = 0; r < 4; r++) {
                const int row = tile_m + wm + mi * 16 + quad * 4 + r;
                P[(size_t)row * 1024 + col] = f2b(acc[mi][ni][r] + bv);
            }
        }
    }
}

// ---------------- LayerNorm family (bf16 X + bf16 partials) ----------------
template<bool FINAL, int NR>
__global__ void ln_kernel(const unsigned short* __restrict__ Xb,
                          const unsigned short* __restrict__ Rbase, size_t rstride,
                          const float* __restrict__ g, const float* __restrict__ be,
                          unsigned short* __restrict__ ob16,
                          const float* __restrict__ hidden, float* __restrict__ fout) {
    __shared__ float sb1[4], sb2[4];
    const int row = blockIdx.x, t = threadIdx.x;
    const size_t base = (size_t)row * 1024 + t * 4;

    ushort4 xv = *(const ushort4*)(Xb + base);
    float x0 = b2f(xv.x), x1 = b2f(xv.y), x2 = b2f(xv.z), x3 = b2f(xv.w);
#pragma unroll
    for (int r = 0; r < NR; r++) {
        ushort4 rv = *(const ushort4*)(Rbase + r * rstride + base);
        x0 += b2f(rv.x); x1 += b2f(rv.y); x2 += b2f(rv.z); x3 += b2f(rv.w);
    }
    float s = x0 + x1 + x2 + x3;
#pragma unroll
    for (int o = 32; o > 0; o >>= 1) s += __shfl_down(s, o);
    if ((t & 63) == 0) sb1[t >> 6] = s;
    __syncthreads();
    const float mu = (sb1[0] + sb1[1] + sb1[2] + sb1[3]) * (1.0f / 1024.0f);

    const float d0 = x0 - mu, d1 = x1 - mu, d2 = x2 - mu, d3 = x3 - mu;
    float s2 = d0 * d0 + d1 * d1 + d2 * d2 + d3 * d3;
#pragma unroll
    for (int o = 32; o > 0; o >>= 1) s2 += __shfl_down(s2, o);
    if ((t & 63) == 0) sb2[t >> 6] = s2;
    __syncthreads();
    const float var = (sb2[0] + sb2[1] + sb2[2] + sb2[3]) * (1.0f / 1024.0f);
    const float rstd = rsqrtf(var + 1e-6f);

    const float4 gv = *(const float4*)(g + t * 4);
    const float4 bv = *(const float4*)(be + t * 4);
    const float y0 = d0 * rstd * gv.x + bv.x;
    const float y1 = d1 * rstd * gv.y + bv.y;
    const float y2 = d2 * rstd * gv.z + bv.z;
    const float y3 = d3 * rstd * gv.w + bv.w;

    if (!FINAL) {
        ushort4 ob; ob.x = f2b(y0); ob.y = f2b(y1); ob.z = f2b(y2); ob.w = f2b(y3);
        *(ushort4*)(ob16 + base) = ob;
    } else {
        const float4 hv = *(const float4*)(hidden + base);
        const float e0 = y0 > 0.0f ? y0 : expm1f(y0);
        const float e1 = y1 > 0.0f ? y1 : expm1f(y1);
        const float e2 = y2 > 0.0f ? y2 : expm1f(y2);
        const float e3 = y3 > 0.0f ? y3 : expm1f(y3);
        float4 o; o.x = hv.x + e0; o.y = hv.y + e1; o.z = hv.z + e2; o.w = hv.w + e3;
        *(float4*)(fout + base) = o;
    }
}

// ---------------- dense edge phase ----------------
__global__ void edge_scatter(const unsigned short* __restrict__ S,
                             const int* __restrict__ src, const int* __restrict__ dst,
                             const int* __restrict__ rel,
                             float* __restrict__ A, float* __restrict__ G) {
    const size_t ZSTR = (size_t)B_SZ * SEXT_M * 1024;
    const int gg = blockIdx.x * 256 + threadIdx.x;   // B*E = 131072
    const int b = gg >> 15;
    const int s = src[gg], d = dst[gg], r = rel[gg];
    const size_t sbase = ((size_t)b * SEXT_M + s) * 1024 + d;
    const size_t tbase = ((size_t)b * SEXT_M + 1024 + r) * 1024 + d;
    const float sval = b2f(S[sbase]) + b2f(S[sbase + ZSTR]);
    const float tval = b2f(S[tbase]) + b2f(S[tbase + ZSTR]);
    float sc = (sval + tval) * (1.0f / 32.0f);
    sc = expf(fminf(fmaxf(sc, -10.0f), 10.0f));
    atomicAdd(&A[((size_t)((b << 10) + d) << 10) + s], sc);
    atomicAdd(&G[((size_t)((b << 10) + d) << 6) + r], sc);
}

// per node: inv = 1/sum_r G[row,r]; Awv[row] = bf16([A*inv | G*inv])  (1088-wide)
__global__ void normalize(const float* __restrict__ A, const float* __restrict__ G,
                          unsigned short* __restrict__ Awv) {
    __shared__ float sInv;
    const int row = blockIdx.x, t = threadIdx.x;
    float v = 0.0f;
    if (t < 64) {
        v = G[(size_t)row * 64 + t];
        float s = v;
#pragma unroll
        for (int o = 1; o < 64; o <<= 1) s += __shfl_xor(s, o);
        if (t == 0) sInv = 1.0f / s;
    }
    __syncthreads();
    const float inv = sInv;
    const size_t obase = (size_t)row * LDA_WV;
    const float4 a = *(const float4*)(A + (size_t)row * 1024 + t * 4);
    ushort4 o;
    o.x = f2b(a.x * inv); o.y = f2b(a.y * inv); o.z = f2b(a.z * inv); o.w = f2b(a.w * inv);
    *(ushort4*)(Awv + obase + t * 4) = o;
    if (t < 16) {
        const float4 gq = *(const float4*)(G + (size_t)row * 64 + t * 4);
        ushort4 og;
        og.x = f2b(gq.x * inv); og.y = f2b(gq.y * inv);
        og.z = f2b(gq.z * inv); og.w = f2b(gq.w * inv);
        *(ushort4*)(Awv + obase + 1024 + t * 4) = og;
    }
}

// ---------------- launch ----------------
extern "C" void kernel_launch(void* const* d_in, const int* in_sizes, int n_in,
                              void* d_out, int out_size, void* d_ws, size_t ws_size,
                              hipStream_t stream) {
    const float* hidden  = (const float*)d_in[0];
    const float* rel_tbl = (const float*)d_in[1];
    const float* Wq = (const float*)d_in[2];
    const float* bq = (const float*)d_in[3];
    const float* Wk = (const float*)d_in[4];
    const float* Wv = (const float*)d_in[5];
    const float* Wo = (const float*)d_in[6];
    const float* bo = (const float*)d_in[7];
    const float* ln0_g = (const float*)d_in[8];
    const float* ln0_b = (const float*)d_in[9];
    const float* ln1_g = (const float*)d_in[10];
    const float* ln1_b = (const float*)d_in[11];
    const float* W1 = (const float*)d_in[12];
    const float* b1 = (const float*)d_in[13];
    const float* W2 = (const float*)d_in[14];
    const float* b2 = (const float*)d_in[15];
    const float* ln2_g = (const float*)d_in[16];
    const float* ln2_b = (const float*)d_in[17];
    const int* esrc = (const int*)d_in[18];
    const int* edst = (const int*)d_in[19];
    const int* erel = (const int*)d_in[20];
    float* out = (float*)d_out;

    // ws lifetime map (peak 121MB) — identical overlay to R12.
    char* ws = (char*)d_ws;
    const size_t MB = 1024 * 1024;
    unsigned short* Xn_b16  = (unsigned short*)(ws + 16 * MB);
    unsigned short* H1      = (unsigned short*)(ws + 0);
    unsigned short* Wqkv_t  = (unsigned short*)(ws + 24 * MB);
    unsigned short* Wo_t    = (unsigned short*)(ws + 30 * MB);
    unsigned short* W1_t    = (unsigned short*)(ws + 32 * MB);
    unsigned short* W2_t    = (unsigned short*)(ws + 40 * MB);
    unsigned short* relbPad = (unsigned short*)(ws + 48 * MB);
    float*          bqkv    = (float*)(ws + 48 * MB + 512 * 1024);
    unsigned short* QKV     = (unsigned short*)(ws + 49 * MB);
    unsigned short* Awv     = (unsigned short*)(ws + 49 * MB);
    unsigned short* Qw2H    = (unsigned short*)(ws + 49 * MB);
    unsigned short* PwoH    = (unsigned short*)(ws + 66 * MB);
    unsigned short* SxH     = (unsigned short*)(ws + 73 * MB);
    unsigned short* Bwvp    = (unsigned short*)(ws + 92 * MB);
    float*          Amat    = (float*)(ws + 101 * MB);
    float*          Gmat    = (float*)(ws + 117 * MB);
    unsigned short* Out_b16 = (unsigned short*)(ws + 113 * MB);

    const size_t PSTRIDE_H = 4u * 1024 * 1024;   // 8MB bf16 partial, in ushorts
    const dim3 blk(256);
    const dim3 blk512(512);

    // ---- fused prep ----
    prep_all<<<17996, blk, 0, stream>>>(Wq, Wk, Wv, Wo, W1, W2, rel_tbl, bq,
                                        hidden, ln0_g, ln0_b,
                                        Wqkv_t, Wo_t, W1_t, W2_t, relbPad, bqkv,
                                        Xn_b16, Amat);
    // ---- QKV GEMM (256² 2-barrier phases: M=4096,N=3072,K=1024 -> 192 blocks) ----
    gemm256<false, false><<<dim3(192), blk512, 0, stream>>>(
        Xn_b16, 1024, Wqkv_t, 1024, bqkv, QKV, 0, 3072, 1024, 12);
    // ---- S_ext GEMM + W' GEMM (merged, 128² core) ----
    sext_w<<<864, blk, 0, stream>>>(QKV, relbPad, Wo_t, SxH, Bwvp, 512);
    // ---- scatter scores into pre-zeroed A,G ----
    edge_scatter<<<512, blk, 0, stream>>>(SxH, esrc, edst, erel, Amat, Gmat);
    // ---- normalize -> Awv [4096,1088] ----
    normalize<<<M_ROWS, blk, 0, stream>>>(Amat, Gmat, Awv);
    // ---- wv': attention out = Awv @ Bwv'^T + bo (asym split-K=2 -> PwoH, 128² core) ----
    gemm_wv_splitk<<<dim3(256, 1, 2), blk, 0, stream>>>(Awv, Bwvp, bo, PwoH, PSTRIDE_H);
    // ---- LN1: LN(Xn + Pwo) -> Out_b16 ----
    ln_kernel<false, 2><<<M_ROWS, blk, 0, stream>>>(Xn_b16, PwoH, PSTRIDE_H, ln1_g, ln1_b,
                                                    Out_b16, nullptr, nullptr);
    // ---- FFN1 (256² 2-barrier phases: M=4096,N=4096,K=1024 -> 256 blocks) ----
    gemm256<true, false><<<dim3(256), blk512, 0, stream>>>(
        Out_b16, 1024, W1_t, 1024, b1, H1, 0, 4096, 1024, 16);
    // ---- W2 (256² 2-barrier phases split-K=4: 4x M=4096,N=1024,Kc=1024 -> 256 blocks) ----
    gemm256<false, true><<<dim3(64, 1, 4), blk512, 0, stream>>>(
        H1, 4096, W2_t, 4096, b2, Qw2H, PSTRIDE_H, 1024, 1024, 4);
    // ---- LN2(out + sum Qw2) + elu + residual ----
    ln_kernel<true, 4><<<M_ROWS, blk, 0, stream>>>(Out_b16, Qw2H, PSTRIDE_H, ln2_g, ln2_b,
                                                   nullptr, hidden, out);
    (void)in_sizes; (void)n_in; (void)out_size; (void)ws_size;
}